// Round 1
// baseline (709.554 us; speedup 1.0000x reference)
//
#include <hip/hip_runtime.h>

constexpr int H = 256, MSGC = 64, KEYC = 16, CMB = 320;
constexpr float LN_EPS = 1e-5f;
constexpr float INV_SQRT_K = 0.25f;   // 1/sqrt(16)

// ---------------- proj: msgs/keys/qrys = h @ W*.T + b ----------------
__global__ __launch_bounds__(128) void proj_kernel(
    const float* __restrict__ h,
    const float* __restrict__ Wm, const float* __restrict__ bm,
    const float* __restrict__ Wk, const float* __restrict__ bk,
    const float* __restrict__ Wq, const float* __restrict__ bq,
    float* __restrict__ msgs, float* __restrict__ keys, float* __restrict__ qrys,
    int n)
{
    __shared__ float hl[16 * H];
    const int t = threadIdx.x;
    const int r0 = blockIdx.x * 16;
    const float4* src = (const float4*)(h + (size_t)r0 * H);
    float4* dst = (float4*)hl;
#pragma unroll
    for (int u = 0; u < 8; ++u) dst[t + 128 * u] = src[t + 128 * u];
    __syncthreads();
    if (t < 96) {
        const float* Wp;
        if (t < 64)      Wp = Wm + (size_t)t * H;
        else if (t < 80) Wp = Wk + (size_t)(t - 64) * H;
        else             Wp = Wq + (size_t)(t - 80) * H;
        float acc[16];
#pragma unroll
        for (int r = 0; r < 16; ++r) acc[r] = 0.f;
        const float4* W4 = (const float4*)Wp;
        const float4* h4 = (const float4*)hl;
        for (int k4 = 0; k4 < 64; ++k4) {
            float4 w = W4[k4];
#pragma unroll
            for (int r = 0; r < 16; ++r) {
                float4 hv = h4[r * 64 + k4];
                acc[r] += hv.x * w.x + hv.y * w.y + hv.z * w.z + hv.w * w.w;
            }
        }
        if (t < 64) {
            float b = bm[t];
#pragma unroll
            for (int r = 0; r < 16; ++r) msgs[(size_t)(r0 + r) * MSGC + t] = acc[r] + b;
        } else if (t < 80) {
            float b = bk[t - 64];
#pragma unroll
            for (int r = 0; r < 16; ++r) keys[(size_t)(r0 + r) * KEYC + (t - 64)] = acc[r] + b;
        } else {
            float b = bq[t - 80];
#pragma unroll
            for (int r = 0; r < 16; ++r) qrys[(size_t)(r0 + r) * KEYC + (t - 80)] = acc[r] + b;
        }
    }
}

// ---------------- pass1: per-row softmax max & denom ----------------
__global__ __launch_bounds__(256) void pass1_kernel(
    const float* __restrict__ qrys, const float* __restrict__ keys,
    float* __restrict__ rowm, float* __restrict__ rowl, int n)
{
    __shared__ float4 q4[16 * 4];
    __shared__ float redm[16][4], redl[16][4];
    const int t = threadIdx.x;
    const int i0 = blockIdx.x * 16;
    if (t < 64) q4[t] = ((const float4*)(qrys + (size_t)i0 * KEYC))[t];
    __syncthreads();
    float m[16], l[16];
#pragma unroll
    for (int il = 0; il < 16; ++il) { m[il] = -1e30f; l[il] = 0.f; }
    const int iters = n / 256;
    for (int it = 0; it < iters; ++it) {
        const int j = it * 256 + t;
        const float4* kp = (const float4*)(keys + (size_t)j * KEYC);
        float4 ka = kp[0], kb = kp[1], kc = kp[2], kd = kp[3];
#pragma unroll 8
        for (int il = 0; il < 16; ++il) {
            float4 qa = q4[il * 4 + 0], qb = q4[il * 4 + 1];
            float4 qc = q4[il * 4 + 2], qd = q4[il * 4 + 3];
            float s = qa.x*ka.x + qa.y*ka.y + qa.z*ka.z + qa.w*ka.w
                    + qb.x*kb.x + qb.y*kb.y + qb.z*kb.z + qb.w*kb.w
                    + qc.x*kc.x + qc.y*kc.y + qc.z*kc.z + qc.w*kc.w
                    + qd.x*kd.x + qd.y*kd.y + qd.z*kd.z + qd.w*kd.w;
            s *= INV_SQRT_K;
            float nm = fmaxf(m[il], s);
            l[il] = l[il] * __expf(m[il] - nm) + __expf(s - nm);
            m[il] = nm;
        }
    }
    // butterfly reduce (m,l) across the 64-lane wave
#pragma unroll
    for (int il = 0; il < 16; ++il) {
#pragma unroll
        for (int d = 1; d < 64; d <<= 1) {
            float om = __shfl_xor(m[il], d, 64);
            float ol = __shfl_xor(l[il], d, 64);
            float nm = fmaxf(m[il], om);
            l[il] = l[il] * __expf(m[il] - nm) + ol * __expf(om - nm);
            m[il] = nm;
        }
    }
    const int w = t >> 6, lane = t & 63;
    if (lane == 0) {
#pragma unroll
        for (int il = 0; il < 16; ++il) { redm[il][w] = m[il]; redl[il][w] = l[il]; }
    }
    __syncthreads();
    if (t < 16) {
        float fm = redm[t][0], fl = redl[t][0];
#pragma unroll
        for (int w2 = 1; w2 < 4; ++w2) {
            float om = redm[t][w2], ol = redl[t][w2];
            float nm = fmaxf(fm, om);
            fl = fl * __expf(fm - nm) + ol * __expf(om - nm);
            fm = nm;
        }
        rowm[i0 + t] = fm;
        rowl[i0 + t] = fl;
    }
}

// ---------------- pass2: P=softmax tile, AGG += P @ msgs, optional attn write ----------------
template <bool WRITE_ATTN>
__global__ __launch_bounds__(256) void pass2_kernel(
    const float* __restrict__ qrys, const float* __restrict__ keys,
    const float* __restrict__ msgs, const float* __restrict__ rowm,
    const float* __restrict__ rowl, float* __restrict__ agg4,
    float* __restrict__ attn, int n)
{
    __shared__ float  q[64 * KEYC];        // 4 KB
    __shared__ float  ml[64], rl[64];
    __shared__ float  P[64 * 129];         // 33 KB, stride 129 kills column bank conflicts
    __shared__ float4 M4[128 * 16];        // 32 KB msgs tile
    const int t = threadIdx.x;
    const int i0 = blockIdx.x * 64;
    const int nj = n / 4;                  // j-chunk per blockIdx.y
    const int jbase = blockIdx.y * nj;

    ((float4*)q)[t] = ((const float4*)(qrys + (size_t)i0 * KEYC))[t];
    if (t < 64) { ml[t] = rowm[i0 + t]; rl[t] = 1.f / rowl[i0 + t]; }
    __syncthreads();

    float acc[4][4];
#pragma unroll
    for (int u = 0; u < 4; ++u)
#pragma unroll
        for (int v = 0; v < 4; ++v) acc[u][v] = 0.f;

    const int cg = t & 15, ilg = t >> 4;
    const int c0 = cg * 4, il0 = ilg * 4;
    const int jj = t & 127, ilh = (t >> 7) * 32;

    for (int jt = 0; jt < nj / 128; ++jt) {
        const int j0 = jbase + jt * 128;
        // stage msgs tile (contiguous 32 KB)
        const float4* msrc = (const float4*)(msgs + (size_t)j0 * MSGC);
#pragma unroll
        for (int u = 0; u < 8; ++u) M4[t + 256 * u] = msrc[t + 256 * u];
        // P tile: this thread owns column jj, rows ilh..ilh+31
        const float4* kp = (const float4*)(keys + (size_t)(j0 + jj) * KEYC);
        float4 ka = kp[0], kb = kp[1], kc = kp[2], kd = kp[3];
#pragma unroll 8
        for (int u = 0; u < 32; ++u) {
            const int il = ilh + u;
            const float4* qq = (const float4*)(q + il * KEYC);
            float4 qa = qq[0], qb = qq[1], qc = qq[2], qd = qq[3];
            float s = qa.x*ka.x + qa.y*ka.y + qa.z*ka.z + qa.w*ka.w
                    + qb.x*kb.x + qb.y*kb.y + qb.z*kb.z + qb.w*kb.w
                    + qc.x*kc.x + qc.y*kc.y + qc.z*kc.z + qc.w*kc.w
                    + qd.x*kd.x + qd.y*kd.y + qd.z*kd.z + qd.w*kd.w;
            s *= INV_SQRT_K;
            float p = __expf(s - ml[il]) * rl[il];
            P[il * 129 + jj] = p;
            if (WRITE_ATTN) attn[(size_t)(i0 + il) * n + (j0 + jj)] = p;
        }
        __syncthreads();
        // AGG(64x64) += P(64x128) @ M(128x64), 4x4 per thread
#pragma unroll 4
        for (int j = 0; j < 128; ++j) {
            float pv0 = P[(il0 + 0) * 129 + j];
            float pv1 = P[(il0 + 1) * 129 + j];
            float pv2 = P[(il0 + 2) * 129 + j];
            float pv3 = P[(il0 + 3) * 129 + j];
            float4 mv = M4[j * 16 + cg];
            acc[0][0] += pv0 * mv.x; acc[0][1] += pv0 * mv.y; acc[0][2] += pv0 * mv.z; acc[0][3] += pv0 * mv.w;
            acc[1][0] += pv1 * mv.x; acc[1][1] += pv1 * mv.y; acc[1][2] += pv1 * mv.z; acc[1][3] += pv1 * mv.w;
            acc[2][0] += pv2 * mv.x; acc[2][1] += pv2 * mv.y; acc[2][2] += pv2 * mv.z; acc[2][3] += pv2 * mv.w;
            acc[3][0] += pv3 * mv.x; acc[3][1] += pv3 * mv.y; acc[3][2] += pv3 * mv.z; acc[3][3] += pv3 * mv.w;
        }
        __syncthreads();
    }
    float* ap = agg4 + (size_t)blockIdx.y * (size_t)n * MSGC + (size_t)(i0 + il0) * MSGC + c0;
#pragma unroll
    for (int u = 0; u < 4; ++u)
        *((float4*)(ap + (size_t)u * MSGC)) = make_float4(acc[u][0], acc[u][1], acc[u][2], acc[u][3]);
}

// ---------------- aggln: z = [h, agg] @ W_agg.T + b; LayerNorm; ReLU ----------------
__global__ __launch_bounds__(256) void aggln_kernel(
    const float* __restrict__ h, const float* __restrict__ agg4,
    const float* __restrict__ Wa, const float* __restrict__ ba,
    const float* __restrict__ g, const float* __restrict__ b,
    float* __restrict__ hout, int n)
{
    __shared__ float comb[16 * CMB];       // 20 KB
    __shared__ float red1[16][4], red2[16][4];
    __shared__ float mus[16], rss[16];
    const int t = threadIdx.x;
    const int r0 = blockIdx.x * 16;
    // h part: contiguous 16x256 tile
    const float4* hsrc = (const float4*)(h + (size_t)r0 * H);
#pragma unroll
    for (int u = 0; u < 4; ++u) {
        const int idx = t + 256 * u;       // float4 index in 16x64 grid
        const int r = idx >> 6, kk = idx & 63;
        ((float4*)(comb + r * CMB))[kk] = hsrc[idx];
    }
    // agg part: sum of 4 partials
    for (int idx = t; idx < 16 * 64; idx += 256) {
        const int r = idx >> 6, c = idx & 63;
        float s = 0.f;
#pragma unroll
        for (int p = 0; p < 4; ++p)
            s += agg4[(size_t)p * n * MSGC + (size_t)(r0 + r) * MSGC + c];
        comb[r * CMB + 256 + c] = s;
    }
    __syncthreads();
    float acc[16];
#pragma unroll
    for (int r = 0; r < 16; ++r) acc[r] = 0.f;
    const float4* W4 = (const float4*)(Wa + (size_t)t * CMB);
    for (int k4 = 0; k4 < 80; ++k4) {
        float4 w = W4[k4];
#pragma unroll
        for (int r = 0; r < 16; ++r) {
            float4 cv = ((const float4*)(comb + r * CMB))[k4];
            acc[r] += cv.x*w.x + cv.y*w.y + cv.z*w.z + cv.w*w.w;
        }
    }
    const float bb = ba[t];
#pragma unroll
    for (int r = 0; r < 16; ++r) acc[r] += bb;
    // LayerNorm reductions across the 256 outputs
#pragma unroll
    for (int r = 0; r < 16; ++r) {
        float s1 = acc[r], s2 = acc[r] * acc[r];
#pragma unroll
        for (int d = 1; d < 64; d <<= 1) { s1 += __shfl_xor(s1, d, 64); s2 += __shfl_xor(s2, d, 64); }
        if ((t & 63) == 0) { red1[r][t >> 6] = s1; red2[r][t >> 6] = s2; }
    }
    __syncthreads();
    if (t < 16) {
        float s1 = red1[t][0] + red1[t][1] + red1[t][2] + red1[t][3];
        float s2 = red2[t][0] + red2[t][1] + red2[t][2] + red2[t][3];
        float mu = s1 * (1.f / 256.f);
        float var = s2 * (1.f / 256.f) - mu * mu;
        mus[t] = mu;
        rss[t] = rsqrtf(var + LN_EPS);
    }
    __syncthreads();
    const float gv = g[t], bv = b[t];
#pragma unroll
    for (int r = 0; r < 16; ++r) {
        float v = (acc[r] - mus[r]) * rss[r] * gv + bv;
        hout[(size_t)(r0 + r) * H + t] = fmaxf(v, 0.f);
    }
}

extern "C" void kernel_launch(void* const* d_in, const int* in_sizes, int n_in,
                              void* d_out, int out_size, void* d_ws, size_t ws_size,
                              hipStream_t stream)
{
    const float* hs = (const float*)d_in[0];
    const float* Wm = (const float*)d_in[1];
    const float* bm = (const float*)d_in[2];
    const float* Wk = (const float*)d_in[3];
    const float* bk = (const float*)d_in[4];
    const float* Wq = (const float*)d_in[5];
    const float* bq = (const float*)d_in[6];
    const float* Wa = (const float*)d_in[7];
    const float* ba = (const float*)d_in[8];
    const float* lg = (const float*)d_in[9];
    const float* lb = (const float*)d_in[10];
    const int n = in_sizes[0] / H;         // 8192

    float* ws = (float*)d_ws;
    float* h2   = ws; ws += (size_t)n * H;
    float* msgs = ws; ws += (size_t)n * MSGC;
    float* keys = ws; ws += (size_t)n * KEYC;
    float* qrys = ws; ws += (size_t)n * KEYC;
    float* rowm = ws; ws += n;
    float* rowl = ws; ws += n;
    float* agg4 = ws; ws += (size_t)4 * n * MSGC;

    float* hOut = (float*)d_out;
    float* attn = hOut + (size_t)n * H;

    for (int round = 0; round < 2; ++round) {
        const float* hc = (round == 0) ? hs : h2;
        float*       hn = (round == 0) ? h2 : hOut;
        proj_kernel<<<n / 16, 128, 0, stream>>>(hc, Wm, bm, Wk, bk, Wq, bq, msgs, keys, qrys, n);
        pass1_kernel<<<n / 16, 256, 0, stream>>>(qrys, keys, rowm, rowl, n);
        if (round == 0)
            pass2_kernel<false><<<dim3(n / 64, 4), 256, 0, stream>>>(qrys, keys, msgs, rowm, rowl, agg4, attn, n);
        else
            pass2_kernel<true><<<dim3(n / 64, 4), 256, 0, stream>>>(qrys, keys, msgs, rowm, rowl, agg4, attn, n);
        aggln_kernel<<<n / 16, 256, 0, stream>>>(hc, agg4, Wa, ba, lg, lb, hn, n);
    }
}

// Round 2
// 482.828 us; speedup vs baseline: 1.4696x; 1.4696x over previous
//
#include <hip/hip_runtime.h>

constexpr int H = 256, MSGC = 64, CMB = 320;
constexpr float LN_EPS = 1e-5f;

typedef __attribute__((ext_vector_type(8))) short bf16x8;
typedef __attribute__((ext_vector_type(4))) float f32x4;

__device__ inline ushort f2bf(float x) {
    union { float f; unsigned u; } v; v.f = x;
    unsigned r = v.u + 0x7fffu + ((v.u >> 16) & 1u);
    return (ushort)(r >> 16);
}
__device__ inline float bf2f(ushort h) {
    union { unsigned u; float f; } v; v.u = ((unsigned)h) << 16;
    return v.f;
}

// ---------------- proj: produce split-bf16 q/k and bf16 msgs^T ----------------
__global__ __launch_bounds__(128) void proj_kernel(
    const float* __restrict__ h,
    const float* __restrict__ Wm, const float* __restrict__ bm,
    const float* __restrict__ Wk, const float* __restrict__ bk,
    const float* __restrict__ Wq, const float* __restrict__ bq,
    ushort* __restrict__ msgsT, ushort* __restrict__ kh, ushort* __restrict__ kl,
    ushort* __restrict__ qh, ushort* __restrict__ ql, int n)
{
    __shared__ float hl[16 * H];
    const int t = threadIdx.x;
    const int r0 = blockIdx.x * 16;
    const float4* src = (const float4*)(h + (size_t)r0 * H);
    float4* dst = (float4*)hl;
#pragma unroll
    for (int u = 0; u < 8; ++u) dst[t + 128 * u] = src[t + 128 * u];
    __syncthreads();
    if (t < 96) {
        const float* Wp;
        if (t < 64)      Wp = Wm + (size_t)t * H;
        else if (t < 80) Wp = Wk + (size_t)(t - 64) * H;
        else             Wp = Wq + (size_t)(t - 80) * H;
        float acc[16];
#pragma unroll
        for (int r = 0; r < 16; ++r) acc[r] = 0.f;
        const float4* W4 = (const float4*)Wp;
        const float4* h4 = (const float4*)hl;
        for (int k4 = 0; k4 < 64; ++k4) {
            float4 w = W4[k4];
#pragma unroll
            for (int r = 0; r < 16; ++r) {
                float4 hv = h4[r * 64 + k4];
                acc[r] += hv.x * w.x + hv.y * w.y + hv.z * w.z + hv.w * w.w;
            }
        }
        if (t < 64) {
            float b = bm[t];
#pragma unroll
            for (int r = 0; r < 16; ++r) msgsT[(size_t)t * n + r0 + r] = f2bf(acc[r] + b);
        } else if (t < 80) {
            const int cc = t - 64; float b = bk[cc];
#pragma unroll
            for (int r = 0; r < 16; ++r) {
                float v = acc[r] + b;
                ushort hi = f2bf(v);
                kh[(size_t)(r0 + r) * 16 + cc] = hi;
                kl[(size_t)(r0 + r) * 16 + cc] = f2bf(v - bf2f(hi));
            }
        } else {
            const int cc = t - 80; float b = bq[cc];
#pragma unroll
            for (int r = 0; r < 16; ++r) {
                float v = 0.25f * (acc[r] + b);      // fold 1/sqrt(16) into q
                ushort hi = f2bf(v);
                qh[(size_t)(r0 + r) * 16 + cc] = hi;
                ql[(size_t)(r0 + r) * 16 + cc] = f2bf(v - bf2f(hi));
            }
        }
    }
}

// ---------------- stats: online softmax (m,l) partials via MFMA QK^T ----------------
__global__ __launch_bounds__(256) void stats_kernel(
    const ushort* __restrict__ qh, const ushort* __restrict__ ql,
    const ushort* __restrict__ kh, const ushort* __restrict__ kl,
    float* __restrict__ rowm_p, float* __restrict__ rowl_p, int n)
{
    const int t = threadIdx.x, lane = t & 63, w = t >> 6;
    const int g = lane >> 4, c = lane & 15;
    const int iq = blockIdx.x * 64 + w * 16 + c;
    bf16x8 zer = {0,0,0,0,0,0,0,0};
    f32x4 z4 = {0.f, 0.f, 0.f, 0.f};
    const ushort* qsrc = (g < 2) ? qh : ql;
    bf16x8 a1 = *(const bf16x8*)(qsrc + (size_t)iq * 16 + 8 * (g & 1));
    bf16x8 a2 = (g < 2) ? a1 : zer;
    const int nj = n / 8, jb = blockIdx.y * nj;
    float m[4] = {-1e30f, -1e30f, -1e30f, -1e30f}, l[4] = {0.f, 0.f, 0.f, 0.f};
    for (int js = 0; js < nj; js += 16) {
        const int j = jb + js + c;
        bf16x8 b1 = *(const bf16x8*)(kh + (size_t)j * 16 + 8 * (g & 1));
        bf16x8 b2 = (g < 2) ? *(const bf16x8*)(kl + (size_t)j * 16 + 8 * g) : zer;
        f32x4 d = __builtin_amdgcn_mfma_f32_16x16x32_bf16(a1, b1, z4, 0, 0, 0);
        d = __builtin_amdgcn_mfma_f32_16x16x32_bf16(a2, b2, d, 0, 0, 0);
#pragma unroll
        for (int r = 0; r < 4; ++r) {
            float s = d[r];
            float nm = fmaxf(m[r], s);
            l[r] = l[r] * __expf(m[r] - nm) + __expf(s - nm);
            m[r] = nm;
        }
    }
#pragma unroll
    for (int r = 0; r < 4; ++r) {
#pragma unroll
        for (int d2 = 1; d2 < 16; d2 <<= 1) {
            float om = __shfl_xor(m[r], d2, 64);
            float ol = __shfl_xor(l[r], d2, 64);
            float nm = fmaxf(m[r], om);
            l[r] = l[r] * __expf(m[r] - nm) + ol * __expf(om - nm);
            m[r] = nm;
        }
    }
    if (c == 0) {
        const int q0 = blockIdx.x * 64 + w * 16 + g * 4;
#pragma unroll
        for (int r = 0; r < 4; ++r) {
            rowm_p[(size_t)blockIdx.y * n + q0 + r] = m[r];
            rowl_p[(size_t)blockIdx.y * n + q0 + r] = l[r];
        }
    }
}

__global__ __launch_bounds__(256) void combine_kernel(
    const float* __restrict__ rowm_p, const float* __restrict__ rowl_p,
    float* __restrict__ rowm, float* __restrict__ rowrinv, int n)
{
    const int q = blockIdx.x * 256 + threadIdx.x;
    float m = -1e30f;
#pragma unroll
    for (int p = 0; p < 8; ++p) m = fmaxf(m, rowm_p[(size_t)p * n + q]);
    float l = 0.f;
#pragma unroll
    for (int p = 0; p < 8; ++p) l += rowl_p[(size_t)p * n + q] * __expf(rowm_p[(size_t)p * n + q] - m);
    rowm[q] = m;
    rowrinv[q] = 1.f / l;
}

// ---------------- pass2: MFMA scores -> P(LDS, swizzled f32) -> MFMA PV ----------------
template <bool WRITE_ATTN>
__global__ __launch_bounds__(256) void pass2_kernel(
    const ushort* __restrict__ qh, const ushort* __restrict__ ql,
    const ushort* __restrict__ kh, const ushort* __restrict__ kl,
    const ushort* __restrict__ msgsT, const float* __restrict__ rowm,
    const float* __restrict__ rowrinv, float* __restrict__ agg,
    float* __restrict__ attn, int n)
{
    __shared__ float P[64 * 128];          // 32 KB, XOR-swizzled columns
    const int t = threadIdx.x, lane = t & 63, w = t >> 6;
    const int g = lane >> 4, c = lane & 15;
    const int i0 = blockIdx.x * 64;
    bf16x8 zer = {0,0,0,0,0,0,0,0};
    f32x4 z4 = {0.f, 0.f, 0.f, 0.f};
    const ushort* qsrc = (g < 2) ? qh : ql;
    bf16x8 a1 = *(const bf16x8*)(qsrc + (size_t)(i0 + w * 16 + c) * 16 + 8 * (g & 1));
    bf16x8 a2 = (g < 2) ? a1 : zer;
    float m_r[4], rinv_r[4];
#pragma unroll
    for (int r = 0; r < 4; ++r) {
        const int q = i0 + w * 16 + g * 4 + r;
        m_r[r] = rowm[q];
        rinv_r[r] = rowrinv[q];
    }
    f32x4 accv[4] = {z4, z4, z4, z4};
    const int nj = n / 8, jb = blockIdx.y * nj;
    for (int jt = 0; jt < nj / 128; ++jt) {
        const int j0 = jb + jt * 128;
        // phase A: scores + softmax -> LDS (each wave writes its own 16-row band)
#pragma unroll
        for (int js = 0; js < 8; ++js) {
            const int j = j0 + js * 16 + c;
            bf16x8 b1 = *(const bf16x8*)(kh + (size_t)j * 16 + 8 * (g & 1));
            bf16x8 b2 = (g < 2) ? *(const bf16x8*)(kl + (size_t)j * 16 + 8 * g) : zer;
            f32x4 d = __builtin_amdgcn_mfma_f32_16x16x32_bf16(a1, b1, z4, 0, 0, 0);
            d = __builtin_amdgcn_mfma_f32_16x16x32_bf16(a2, b2, d, 0, 0, 0);
#pragma unroll
            for (int r = 0; r < 4; ++r) {
                const int row = w * 16 + g * 4 + r;
                const float p = __expf(d[r] - m_r[r]) * rinv_r[r];
                const int col = js * 16 + c;
                P[row * 128 + (col ^ ((row & 7) << 2))] = p;
            }
        }
        if (WRITE_ATTN) {
            __syncthreads();
#pragma unroll
            for (int u = 0; u < 8; ++u) {
                const int row = (t >> 5) + u * 8;
                const int colb = (t & 31) * 4;
                float4 v = *(const float4*)&P[row * 128 + (colb ^ ((row & 7) << 2))];
                *(float4*)(attn + (size_t)(i0 + row) * n + j0 + colb) = v;
            }
        }
        // phase B: PV, each wave consumes only its own band (no barrier needed in r1)
#pragma unroll
        for (int ks = 0; ks < 4; ++ks) {
            const int arow = w * 16 + c;
            const int sw = (arow & 7) << 2;
            const int colb = ks * 32 + 8 * g;
            float4 f0 = *(const float4*)&P[arow * 128 + ((colb) ^ sw)];
            float4 f1 = *(const float4*)&P[arow * 128 + ((colb + 4) ^ sw)];
            bf16x8 af;
            af[0] = (short)f2bf(f0.x); af[1] = (short)f2bf(f0.y);
            af[2] = (short)f2bf(f0.z); af[3] = (short)f2bf(f0.w);
            af[4] = (short)f2bf(f1.x); af[5] = (short)f2bf(f1.y);
            af[6] = (short)f2bf(f1.z); af[7] = (short)f2bf(f1.w);
            const int jk = j0 + ks * 32 + 8 * g;
#pragma unroll
            for (int mt = 0; mt < 4; ++mt) {
                bf16x8 bfr = *(const bf16x8*)(msgsT + (size_t)(mt * 16 + c) * n + jk);
                accv[mt] = __builtin_amdgcn_mfma_f32_16x16x32_bf16(af, bfr, accv[mt], 0, 0, 0);
            }
        }
        if (WRITE_ATTN) __syncthreads();
    }
#pragma unroll
    for (int mt = 0; mt < 4; ++mt)
#pragma unroll
        for (int r = 0; r < 4; ++r) {
            const int row = w * 16 + g * 4 + r;
            agg[((size_t)blockIdx.y * n + i0 + row) * MSGC + mt * 16 + c] = accv[mt][r];
        }
}

// ---------------- aggln: z = [h, agg] @ W_agg.T + b; LayerNorm; ReLU ----------------
__global__ __launch_bounds__(256) void aggln_kernel(
    const float* __restrict__ h, const float* __restrict__ agg8,
    const float* __restrict__ Wa, const float* __restrict__ ba,
    const float* __restrict__ g, const float* __restrict__ b,
    float* __restrict__ hout, int n)
{
    __shared__ float comb[16 * CMB];
    __shared__ float red1[16][4], red2[16][4];
    __shared__ float mus[16], rss[16];
    const int t = threadIdx.x;
    const int r0 = blockIdx.x * 16;
    const float4* hsrc = (const float4*)(h + (size_t)r0 * H);
#pragma unroll
    for (int u = 0; u < 4; ++u) {
        const int idx = t + 256 * u;
        const int r = idx >> 6, kk = idx & 63;
        ((float4*)(comb + r * CMB))[kk] = hsrc[idx];
    }
    for (int idx = t; idx < 16 * 64; idx += 256) {
        const int r = idx >> 6, c = idx & 63;
        float s = 0.f;
#pragma unroll
        for (int p = 0; p < 8; ++p)
            s += agg8[(size_t)p * n * MSGC + (size_t)(r0 + r) * MSGC + c];
        comb[r * CMB + 256 + c] = s;
    }
    __syncthreads();
    float acc[16];
#pragma unroll
    for (int r = 0; r < 16; ++r) acc[r] = 0.f;
    const float4* W4 = (const float4*)(Wa + (size_t)t * CMB);
    for (int k4 = 0; k4 < 80; ++k4) {
        float4 w = W4[k4];
#pragma unroll
        for (int r = 0; r < 16; ++r) {
            float4 cv = ((const float4*)(comb + r * CMB))[k4];
            acc[r] += cv.x * w.x + cv.y * w.y + cv.z * w.z + cv.w * w.w;
        }
    }
    const float bb = ba[t];
#pragma unroll
    for (int r = 0; r < 16; ++r) acc[r] += bb;
#pragma unroll
    for (int r = 0; r < 16; ++r) {
        float s1 = acc[r], s2 = acc[r] * acc[r];
#pragma unroll
        for (int d = 1; d < 64; d <<= 1) { s1 += __shfl_xor(s1, d, 64); s2 += __shfl_xor(s2, d, 64); }
        if ((t & 63) == 0) { red1[r][t >> 6] = s1; red2[r][t >> 6] = s2; }
    }
    __syncthreads();
    if (t < 16) {
        float s1 = red1[t][0] + red1[t][1] + red1[t][2] + red1[t][3];
        float s2 = red2[t][0] + red2[t][1] + red2[t][2] + red2[t][3];
        float mu = s1 * (1.f / 256.f);
        float var = s2 * (1.f / 256.f) - mu * mu;
        mus[t] = mu;
        rss[t] = rsqrtf(var + LN_EPS);
    }
    __syncthreads();
    const float gv = g[t], bv = b[t];
#pragma unroll
    for (int r = 0; r < 16; ++r) {
        float v = (acc[r] - mus[r]) * rss[r] * gv + bv;
        hout[(size_t)(r0 + r) * H + t] = fmaxf(v, 0.f);
    }
}

extern "C" void kernel_launch(void* const* d_in, const int* in_sizes, int n_in,
                              void* d_out, int out_size, void* d_ws, size_t ws_size,
                              hipStream_t stream)
{
    const float* hs = (const float*)d_in[0];
    const float* Wm = (const float*)d_in[1];
    const float* bm = (const float*)d_in[2];
    const float* Wk = (const float*)d_in[3];
    const float* bk = (const float*)d_in[4];
    const float* Wq = (const float*)d_in[5];
    const float* bq = (const float*)d_in[6];
    const float* Wa = (const float*)d_in[7];
    const float* ba = (const float*)d_in[8];
    const float* lg = (const float*)d_in[9];
    const float* lb = (const float*)d_in[10];
    const int n = in_sizes[0] / H;         // 8192

    char* wp = (char*)d_ws;
    auto alloc = [&](size_t bytes) { void* p = (void*)wp; wp += (bytes + 255) & ~(size_t)255; return p; };
    float*  h2     = (float*)alloc((size_t)n * H * 4);
    ushort* qh     = (ushort*)alloc((size_t)n * 16 * 2);
    ushort* ql     = (ushort*)alloc((size_t)n * 16 * 2);
    ushort* kh     = (ushort*)alloc((size_t)n * 16 * 2);
    ushort* kl     = (ushort*)alloc((size_t)n * 16 * 2);
    ushort* msgsT  = (ushort*)alloc((size_t)MSGC * n * 2);
    float*  rowm_p = (float*)alloc((size_t)8 * n * 4);
    float*  rowl_p = (float*)alloc((size_t)8 * n * 4);
    float*  rowm   = (float*)alloc((size_t)n * 4);
    float*  rowri  = (float*)alloc((size_t)n * 4);
    float*  agg    = (float*)alloc((size_t)8 * n * MSGC * 4);

    float* hOut = (float*)d_out;
    float* attn = hOut + (size_t)n * H;

    for (int round = 0; round < 2; ++round) {
        const float* hc = (round == 0) ? hs : h2;
        float*       hn = (round == 0) ? h2 : hOut;
        proj_kernel<<<n / 16, 128, 0, stream>>>(hc, Wm, bm, Wk, bk, Wq, bq,
                                                msgsT, kh, kl, qh, ql, n);
        stats_kernel<<<dim3(n / 64, 8), 256, 0, stream>>>(qh, ql, kh, kl, rowm_p, rowl_p, n);
        combine_kernel<<<n / 256, 256, 0, stream>>>(rowm_p, rowl_p, rowm, rowri, n);
        if (round == 0)
            pass2_kernel<false><<<dim3(n / 64, 8), 256, 0, stream>>>(qh, ql, kh, kl, msgsT,
                                                                     rowm, rowri, agg, attn, n);
        else
            pass2_kernel<true><<<dim3(n / 64, 8), 256, 0, stream>>>(qh, ql, kh, kl, msgsT,
                                                                    rowm, rowri, agg, attn, n);
        aggln_kernel<<<n / 16, 256, 0, stream>>>(hc, agg, Wa, ba, lg, lb, hn, n);
    }
}

// Round 3
// 480.532 us; speedup vs baseline: 1.4766x; 1.0048x over previous
//
#include <hip/hip_runtime.h>

constexpr int H = 256, MSGC = 64, CMB = 320;
constexpr float LN_EPS = 1e-5f;
// fold 1/sqrt(16) AND log2(e) into q so softmax exps are single v_exp_f32 (exp2)
constexpr float QSCALE = 0.25f * 1.4426950408889634f;

typedef __attribute__((ext_vector_type(8))) short bf16x8;
typedef __attribute__((ext_vector_type(4))) float f32x4;

__device__ inline ushort f2bf(float x) {
    union { float f; unsigned u; } v; v.f = x;
    unsigned r = v.u + 0x7fffu + ((v.u >> 16) & 1u);
    return (ushort)(r >> 16);
}
__device__ inline float bf2f(ushort h) {
    union { unsigned u; float f; } v; v.u = ((unsigned)h) << 16;
    return v.f;
}

// ---------------- proj: split-bf16 q/k (q pre-scaled) and bf16 msgs^T ----------------
__global__ __launch_bounds__(128) void proj_kernel(
    const float* __restrict__ h,
    const float* __restrict__ Wm, const float* __restrict__ bm,
    const float* __restrict__ Wk, const float* __restrict__ bk,
    const float* __restrict__ Wq, const float* __restrict__ bq,
    ushort* __restrict__ msgsT, ushort* __restrict__ kh, ushort* __restrict__ kl,
    ushort* __restrict__ qh, ushort* __restrict__ ql, int n)
{
    __shared__ float hl[16 * H];
    const int t = threadIdx.x;
    const int r0 = blockIdx.x * 16;
    const float4* src = (const float4*)(h + (size_t)r0 * H);
    float4* dst = (float4*)hl;
#pragma unroll
    for (int u = 0; u < 8; ++u) dst[t + 128 * u] = src[t + 128 * u];
    __syncthreads();
    if (t < 96) {
        const float* Wp;
        if (t < 64)      Wp = Wm + (size_t)t * H;
        else if (t < 80) Wp = Wk + (size_t)(t - 64) * H;
        else             Wp = Wq + (size_t)(t - 80) * H;
        float acc[16];
#pragma unroll
        for (int r = 0; r < 16; ++r) acc[r] = 0.f;
        const float4* W4 = (const float4*)Wp;
        const float4* h4 = (const float4*)hl;
        for (int k4 = 0; k4 < 64; ++k4) {
            float4 w = W4[k4];
#pragma unroll
            for (int r = 0; r < 16; ++r) {
                float4 hv = h4[r * 64 + k4];   // uniform address -> LDS broadcast (free)
                acc[r] += hv.x * w.x + hv.y * w.y + hv.z * w.z + hv.w * w.w;
            }
        }
        if (t < 64) {
            float b = bm[t];
#pragma unroll
            for (int r = 0; r < 16; ++r) msgsT[(size_t)t * n + r0 + r] = f2bf(acc[r] + b);
        } else if (t < 80) {
            const int cc = t - 64; float b = bk[cc];
#pragma unroll
            for (int r = 0; r < 16; ++r) {
                float v = acc[r] + b;
                ushort hi = f2bf(v);
                kh[(size_t)(r0 + r) * 16 + cc] = hi;
                kl[(size_t)(r0 + r) * 16 + cc] = f2bf(v - bf2f(hi));
            }
        } else {
            const int cc = t - 80; float b = bq[cc];
#pragma unroll
            for (int r = 0; r < 16; ++r) {
                float v = QSCALE * (acc[r] + b);
                ushort hi = f2bf(v);
                qh[(size_t)(r0 + r) * 16 + cc] = hi;
                ql[(size_t)(r0 + r) * 16 + cc] = f2bf(v - bf2f(hi));
            }
        }
    }
}

// ---------------- flash1: round-1 fused online-softmax attention (no attn write) ----------------
__global__ __launch_bounds__(256) void flash1_kernel(
    const ushort* __restrict__ qh, const ushort* __restrict__ ql,
    const ushort* __restrict__ kh, const ushort* __restrict__ kl,
    const ushort* __restrict__ msgsT,
    float* __restrict__ aggO, float* __restrict__ aggM, float* __restrict__ aggL, int n)
{
    __shared__ float P[64 * 64];           // 16 KB, XOR-swizzled; waves own disjoint 16-row bands
    const int t = threadIdx.x, lane = t & 63, w = t >> 6;
    const int g = lane >> 4, c = lane & 15;
    const int i0 = blockIdx.x * 64;
    bf16x8 zer = {0,0,0,0,0,0,0,0};
    f32x4 z4 = {0.f, 0.f, 0.f, 0.f};
    const ushort* qsrc = (g < 2) ? qh : ql;
    bf16x8 a1 = *(const bf16x8*)(qsrc + (size_t)(i0 + w * 16 + c) * 16 + 8 * (g & 1));
    bf16x8 a2 = (g < 2) ? a1 : zer;
    float m[4] = {-1e30f, -1e30f, -1e30f, -1e30f}, l[4] = {0.f, 0.f, 0.f, 0.f};
    f32x4 accv[4] = {z4, z4, z4, z4};
    const int nj = n / 8, jb = blockIdx.y * nj;
    for (int jt = 0; jt < nj / 64; ++jt) {
        const int j0 = jb + jt * 64;
        f32x4 pd[4];
#pragma unroll
        for (int js = 0; js < 4; ++js) {
            const int j = j0 + js * 16 + c;
            bf16x8 b1 = *(const bf16x8*)(kh + (size_t)j * 16 + 8 * (g & 1));
            bf16x8 b2 = (g < 2) ? *(const bf16x8*)(kl + (size_t)j * 16 + 8 * g) : zer;
            pd[js] = __builtin_amdgcn_mfma_f32_16x16x32_bf16(a1, b1, z4, 0, 0, 0);
            pd[js] = __builtin_amdgcn_mfma_f32_16x16x32_bf16(a2, b2, pd[js], 0, 0, 0);
        }
        float sc[4];
#pragma unroll
        for (int r = 0; r < 4; ++r) {
            float tm = fmaxf(fmaxf(pd[0][r], pd[1][r]), fmaxf(pd[2][r], pd[3][r]));
#pragma unroll
            for (int d2 = 1; d2 < 16; d2 <<= 1) tm = fmaxf(tm, __shfl_xor(tm, d2, 64));
            float nm = fmaxf(m[r], tm);
            sc[r] = exp2f(m[r] - nm);
            m[r] = nm;
            l[r] *= sc[r];
        }
#pragma unroll
        for (int mt = 0; mt < 4; ++mt) {
            accv[mt][0] *= sc[0]; accv[mt][1] *= sc[1];
            accv[mt][2] *= sc[2]; accv[mt][3] *= sc[3];
        }
#pragma unroll
        for (int js = 0; js < 4; ++js) {
#pragma unroll
            for (int r = 0; r < 4; ++r) {
                const int row = w * 16 + g * 4 + r;
                float p = exp2f(pd[js][r] - m[r]);
                l[r] += p;
                const int col = js * 16 + c;
                P[row * 64 + (col ^ ((row & 7) << 2))] = p;
            }
        }
        // PV: each wave consumes only its own band -> no barriers anywhere
#pragma unroll
        for (int ks = 0; ks < 2; ++ks) {
            const int arow = w * 16 + c;
            const int sw = (arow & 7) << 2;
            const int colb = ks * 32 + 8 * g;
            float4 f0 = *(const float4*)&P[arow * 64 + ((colb) ^ sw)];
            float4 f1 = *(const float4*)&P[arow * 64 + ((colb + 4) ^ sw)];
            bf16x8 af;
            af[0] = (short)f2bf(f0.x); af[1] = (short)f2bf(f0.y);
            af[2] = (short)f2bf(f0.z); af[3] = (short)f2bf(f0.w);
            af[4] = (short)f2bf(f1.x); af[5] = (short)f2bf(f1.y);
            af[6] = (short)f2bf(f1.z); af[7] = (short)f2bf(f1.w);
            const int jk = j0 + ks * 32 + 8 * g;
#pragma unroll
            for (int mt = 0; mt < 4; ++mt) {
                bf16x8 bfr = *(const bf16x8*)(msgsT + (size_t)(mt * 16 + c) * n + jk);
                accv[mt] = __builtin_amdgcn_mfma_f32_16x16x32_bf16(af, bfr, accv[mt], 0, 0, 0);
            }
        }
    }
    // reduce l across the 16 c-lanes (m is already uniform across them)
#pragma unroll
    for (int r = 0; r < 4; ++r)
#pragma unroll
        for (int d2 = 1; d2 < 16; d2 <<= 1) l[r] += __shfl_xor(l[r], d2, 64);
#pragma unroll
    for (int mt = 0; mt < 4; ++mt)
#pragma unroll
        for (int r = 0; r < 4; ++r)
            aggO[((size_t)blockIdx.y * n + i0 + w * 16 + g * 4 + r) * MSGC + mt * 16 + c] = accv[mt][r];
    if (c == 0) {
#pragma unroll
        for (int r = 0; r < 4; ++r) {
            aggM[(size_t)blockIdx.y * n + i0 + w * 16 + g * 4 + r] = m[r];
            aggL[(size_t)blockIdx.y * n + i0 + w * 16 + g * 4 + r] = l[r];
        }
    }
}

// ---------------- stats (round 2): max-pass then sum-pass, exp out of dep chain ----------------
__global__ __launch_bounds__(256) void stats_kernel(
    const ushort* __restrict__ qh, const ushort* __restrict__ ql,
    const ushort* __restrict__ kh, const ushort* __restrict__ kl,
    float* __restrict__ rowm_p, float* __restrict__ rowl_p, int n)
{
    const int t = threadIdx.x, lane = t & 63, w = t >> 6;
    const int g = lane >> 4, c = lane & 15;
    const int iq = blockIdx.x * 64 + w * 16 + c;
    bf16x8 zer = {0,0,0,0,0,0,0,0};
    f32x4 z4 = {0.f, 0.f, 0.f, 0.f};
    const ushort* qsrc = (g < 2) ? qh : ql;
    bf16x8 a1 = *(const bf16x8*)(qsrc + (size_t)iq * 16 + 8 * (g & 1));
    bf16x8 a2 = (g < 2) ? a1 : zer;
    const int nj = n / 8, jb = blockIdx.y * nj;
    float m[4] = {-1e30f, -1e30f, -1e30f, -1e30f};
    for (int js = 0; js < nj; js += 16) {
        const int j = jb + js + c;
        bf16x8 b1 = *(const bf16x8*)(kh + (size_t)j * 16 + 8 * (g & 1));
        bf16x8 b2 = (g < 2) ? *(const bf16x8*)(kl + (size_t)j * 16 + 8 * g) : zer;
        f32x4 d = __builtin_amdgcn_mfma_f32_16x16x32_bf16(a1, b1, z4, 0, 0, 0);
        d = __builtin_amdgcn_mfma_f32_16x16x32_bf16(a2, b2, d, 0, 0, 0);
#pragma unroll
        for (int r = 0; r < 4; ++r) m[r] = fmaxf(m[r], d[r]);
    }
#pragma unroll
    for (int r = 0; r < 4; ++r)
#pragma unroll
        for (int d2 = 1; d2 < 16; d2 <<= 1) m[r] = fmaxf(m[r], __shfl_xor(m[r], d2, 64));
    float l[4] = {0.f, 0.f, 0.f, 0.f};
    for (int js = 0; js < nj; js += 16) {
        const int j = jb + js + c;
        bf16x8 b1 = *(const bf16x8*)(kh + (size_t)j * 16 + 8 * (g & 1));
        bf16x8 b2 = (g < 2) ? *(const bf16x8*)(kl + (size_t)j * 16 + 8 * g) : zer;
        f32x4 d = __builtin_amdgcn_mfma_f32_16x16x32_bf16(a1, b1, z4, 0, 0, 0);
        d = __builtin_amdgcn_mfma_f32_16x16x32_bf16(a2, b2, d, 0, 0, 0);
#pragma unroll
        for (int r = 0; r < 4; ++r) l[r] += exp2f(d[r] - m[r]);
    }
#pragma unroll
    for (int r = 0; r < 4; ++r)
#pragma unroll
        for (int d2 = 1; d2 < 16; d2 <<= 1) l[r] += __shfl_xor(l[r], d2, 64);
    if (c == 0) {
        const int q0 = blockIdx.x * 64 + w * 16 + g * 4;
#pragma unroll
        for (int r = 0; r < 4; ++r) {
            rowm_p[(size_t)blockIdx.y * n + q0 + r] = m[r];
            rowl_p[(size_t)blockIdx.y * n + q0 + r] = l[r];
        }
    }
}

__global__ __launch_bounds__(256) void combine_kernel(
    const float* __restrict__ rowm_p, const float* __restrict__ rowl_p,
    float* __restrict__ rowm, float* __restrict__ rowrinv, int n)
{
    const int q = blockIdx.x * 256 + threadIdx.x;
    float m = -1e30f;
#pragma unroll
    for (int p = 0; p < 8; ++p) m = fmaxf(m, rowm_p[(size_t)p * n + q]);
    float l = 0.f;
#pragma unroll
    for (int p = 0; p < 8; ++p) l += rowl_p[(size_t)p * n + q] * exp2f(rowm_p[(size_t)p * n + q] - m);
    rowm[q] = m;
    rowrinv[q] = 1.f / l;
}

// ---------------- pass2 (round 2): normalized P -> attn write + PV ----------------
__global__ __launch_bounds__(256) void pass2_kernel(
    const ushort* __restrict__ qh, const ushort* __restrict__ ql,
    const ushort* __restrict__ kh, const ushort* __restrict__ kl,
    const ushort* __restrict__ msgsT, const float* __restrict__ rowm,
    const float* __restrict__ rowrinv, float* __restrict__ aggO,
    float* __restrict__ attn, int n)
{
    __shared__ float P[64 * 128];          // 32 KB
    const int t = threadIdx.x, lane = t & 63, w = t >> 6;
    const int g = lane >> 4, c = lane & 15;
    const int i0 = blockIdx.x * 64;
    bf16x8 zer = {0,0,0,0,0,0,0,0};
    f32x4 z4 = {0.f, 0.f, 0.f, 0.f};
    const ushort* qsrc = (g < 2) ? qh : ql;
    bf16x8 a1 = *(const bf16x8*)(qsrc + (size_t)(i0 + w * 16 + c) * 16 + 8 * (g & 1));
    bf16x8 a2 = (g < 2) ? a1 : zer;
    float m_r[4], rinv_r[4];
#pragma unroll
    for (int r = 0; r < 4; ++r) {
        const int q = i0 + w * 16 + g * 4 + r;
        m_r[r] = rowm[q];
        rinv_r[r] = rowrinv[q];
    }
    f32x4 accv[4] = {z4, z4, z4, z4};
    const int nj = n / 8, jb = blockIdx.y * nj;
    for (int jt = 0; jt < nj / 128; ++jt) {
        const int j0 = jb + jt * 128;
#pragma unroll
        for (int js = 0; js < 8; ++js) {
            const int j = j0 + js * 16 + c;
            bf16x8 b1 = *(const bf16x8*)(kh + (size_t)j * 16 + 8 * (g & 1));
            bf16x8 b2 = (g < 2) ? *(const bf16x8*)(kl + (size_t)j * 16 + 8 * g) : zer;
            f32x4 d = __builtin_amdgcn_mfma_f32_16x16x32_bf16(a1, b1, z4, 0, 0, 0);
            d = __builtin_amdgcn_mfma_f32_16x16x32_bf16(a2, b2, d, 0, 0, 0);
#pragma unroll
            for (int r = 0; r < 4; ++r) {
                const int row = w * 16 + g * 4 + r;
                const float p = exp2f(d[r] - m_r[r]) * rinv_r[r];
                const int col = js * 16 + c;
                P[row * 128 + (col ^ ((row & 7) << 2))] = p;
            }
        }
        __syncthreads();
#pragma unroll
        for (int u = 0; u < 8; ++u) {
            const int row = (t >> 5) + u * 8;
            const int colb = (t & 31) * 4;
            float4 v = *(const float4*)&P[row * 128 + (colb ^ ((row & 7) << 2))];
            *(float4*)(attn + (size_t)(i0 + row) * n + j0 + colb) = v;
        }
#pragma unroll
        for (int ks = 0; ks < 4; ++ks) {
            const int arow = w * 16 + c;
            const int sw = (arow & 7) << 2;
            const int colb = ks * 32 + 8 * g;
            float4 f0 = *(const float4*)&P[arow * 128 + ((colb) ^ sw)];
            float4 f1 = *(const float4*)&P[arow * 128 + ((colb + 4) ^ sw)];
            bf16x8 af;
            af[0] = (short)f2bf(f0.x); af[1] = (short)f2bf(f0.y);
            af[2] = (short)f2bf(f0.z); af[3] = (short)f2bf(f0.w);
            af[4] = (short)f2bf(f1.x); af[5] = (short)f2bf(f1.y);
            af[6] = (short)f2bf(f1.z); af[7] = (short)f2bf(f1.w);
            const int jk = j0 + ks * 32 + 8 * g;
#pragma unroll
            for (int mt = 0; mt < 4; ++mt) {
                bf16x8 bfr = *(const bf16x8*)(msgsT + (size_t)(mt * 16 + c) * n + jk);
                accv[mt] = __builtin_amdgcn_mfma_f32_16x16x32_bf16(af, bfr, accv[mt], 0, 0, 0);
            }
        }
        __syncthreads();
    }
#pragma unroll
    for (int mt = 0; mt < 4; ++mt)
#pragma unroll
        for (int r = 0; r < 4; ++r) {
            const int row = w * 16 + g * 4 + r;
            aggO[((size_t)blockIdx.y * n + i0 + row) * MSGC + mt * 16 + c] = accv[mt][r];
        }
}

// ---------------- aggln: z = [h, agg] @ W_agg.T + b; LayerNorm; ReLU ----------------
template <bool FLASH>
__global__ __launch_bounds__(256) void aggln_kernel(
    const float* __restrict__ h, const float* __restrict__ aggO,
    const float* __restrict__ aggM, const float* __restrict__ aggL,
    const float* __restrict__ Wa, const float* __restrict__ ba,
    const float* __restrict__ g, const float* __restrict__ b,
    float* __restrict__ hout, int n)
{
    __shared__ float comb[16 * CMB];
    __shared__ float red1[16][4], red2[16][4];
    __shared__ float mus[16], rss[16];
    __shared__ float mm[16][8], ll[16][8], wgt[16][8];
    const int t = threadIdx.x;
    const int r0 = blockIdx.x * 16;
    const float4* hsrc = (const float4*)(h + (size_t)r0 * H);
#pragma unroll
    for (int u = 0; u < 4; ++u) {
        const int idx = t + 256 * u;
        const int r = idx >> 6, kk = idx & 63;
        ((float4*)(comb + r * CMB))[kk] = hsrc[idx];
    }
    if (FLASH) {
        if (t < 128) {
            const int r = t >> 3, p = t & 7;
            mm[r][p] = aggM[(size_t)p * n + r0 + r];
            ll[r][p] = aggL[(size_t)p * n + r0 + r];
        }
        __syncthreads();
        if (t < 16) {
            float M = mm[t][0];
#pragma unroll
            for (int p = 1; p < 8; ++p) M = fmaxf(M, mm[t][p]);
            float L = 0.f;
#pragma unroll
            for (int p = 0; p < 8; ++p) L += ll[t][p] * exp2f(mm[t][p] - M);
            const float inv = 1.f / L;
#pragma unroll
            for (int p = 0; p < 8; ++p) wgt[t][p] = exp2f(mm[t][p] - M) * inv;
        }
        __syncthreads();
    }
    for (int idx = t; idx < 16 * 64; idx += 256) {
        const int r = idx >> 6, cc = idx & 63;
        float s = 0.f;
#pragma unroll
        for (int p = 0; p < 8; ++p) {
            float v = aggO[(size_t)p * n * MSGC + (size_t)(r0 + r) * MSGC + cc];
            s += FLASH ? v * wgt[r][p] : v;
        }
        comb[r * CMB + 256 + cc] = s;
    }
    __syncthreads();
    float acc[16];
#pragma unroll
    for (int r = 0; r < 16; ++r) acc[r] = 0.f;
    const float4* W4 = (const float4*)(Wa + (size_t)t * CMB);
    for (int k4 = 0; k4 < 80; ++k4) {
        float4 w = W4[k4];
#pragma unroll
        for (int r = 0; r < 16; ++r) {
            float4 cv = ((const float4*)(comb + r * CMB))[k4];
            acc[r] += cv.x * w.x + cv.y * w.y + cv.z * w.z + cv.w * w.w;
        }
    }
    const float bb = ba[t];
#pragma unroll
    for (int r = 0; r < 16; ++r) acc[r] += bb;
#pragma unroll
    for (int r = 0; r < 16; ++r) {
        float s1 = acc[r], s2 = acc[r] * acc[r];
#pragma unroll
        for (int d = 1; d < 64; d <<= 1) { s1 += __shfl_xor(s1, d, 64); s2 += __shfl_xor(s2, d, 64); }
        if ((t & 63) == 0) { red1[r][t >> 6] = s1; red2[r][t >> 6] = s2; }
    }
    __syncthreads();
    if (t < 16) {
        float s1 = red1[t][0] + red1[t][1] + red1[t][2] + red1[t][3];
        float s2 = red2[t][0] + red2[t][1] + red2[t][2] + red2[t][3];
        float mu = s1 * (1.f / 256.f);
        float var = s2 * (1.f / 256.f) - mu * mu;
        mus[t] = mu;
        rss[t] = rsqrtf(var + LN_EPS);
    }
    __syncthreads();
    const float gv = g[t], bv = b[t];
#pragma unroll
    for (int r = 0; r < 16; ++r) {
        float v = (acc[r] - mus[r]) * rss[r] * gv + bv;
        hout[(size_t)(r0 + r) * H + t] = fmaxf(v, 0.f);
    }
}

extern "C" void kernel_launch(void* const* d_in, const int* in_sizes, int n_in,
                              void* d_out, int out_size, void* d_ws, size_t ws_size,
                              hipStream_t stream)
{
    const float* hs = (const float*)d_in[0];
    const float* Wm = (const float*)d_in[1];
    const float* bm = (const float*)d_in[2];
    const float* Wk = (const float*)d_in[3];
    const float* bk = (const float*)d_in[4];
    const float* Wq = (const float*)d_in[5];
    const float* bq = (const float*)d_in[6];
    const float* Wa = (const float*)d_in[7];
    const float* ba = (const float*)d_in[8];
    const float* lg = (const float*)d_in[9];
    const float* lb = (const float*)d_in[10];
    const int n = in_sizes[0] / H;         // 8192

    char* wp = (char*)d_ws;
    auto alloc = [&](size_t bytes) { void* p = (void*)wp; wp += (bytes + 255) & ~(size_t)255; return p; };
    float*  h2     = (float*)alloc((size_t)n * H * 4);
    ushort* qh     = (ushort*)alloc((size_t)n * 16 * 2);
    ushort* ql     = (ushort*)alloc((size_t)n * 16 * 2);
    ushort* kh     = (ushort*)alloc((size_t)n * 16 * 2);
    ushort* kl     = (ushort*)alloc((size_t)n * 16 * 2);
    ushort* msgsT  = (ushort*)alloc((size_t)MSGC * n * 2);
    float*  rowm_p = (float*)alloc((size_t)8 * n * 4);
    float*  rowl_p = (float*)alloc((size_t)8 * n * 4);
    float*  rowm   = (float*)alloc((size_t)n * 4);
    float*  rowri  = (float*)alloc((size_t)n * 4);
    float*  aggO   = (float*)alloc((size_t)8 * n * MSGC * 4);
    float*  aggM   = (float*)alloc((size_t)8 * n * 4);
    float*  aggL   = (float*)alloc((size_t)8 * n * 4);

    float* hOut = (float*)d_out;
    float* attn = hOut + (size_t)n * H;

    // round 1: fused flash (no stats pass, no attn write)
    proj_kernel<<<n / 16, 128, 0, stream>>>(hs, Wm, bm, Wk, bk, Wq, bq,
                                            msgsT, kh, kl, qh, ql, n);
    flash1_kernel<<<dim3(n / 64, 8), 256, 0, stream>>>(qh, ql, kh, kl, msgsT,
                                                       aggO, aggM, aggL, n);
    aggln_kernel<true><<<n / 16, 256, 0, stream>>>(hs, aggO, aggM, aggL,
                                                   Wa, ba, lg, lb, h2, n);
    // round 2: stats (two-pass) + pass2 (writes normalized attn)
    proj_kernel<<<n / 16, 128, 0, stream>>>(h2, Wm, bm, Wk, bk, Wq, bq,
                                            msgsT, kh, kl, qh, ql, n);
    stats_kernel<<<dim3(n / 64, 8), 256, 0, stream>>>(qh, ql, kh, kl, rowm_p, rowl_p, n);
    combine_kernel<<<n / 256, 256, 0, stream>>>(rowm_p, rowl_p, rowm, rowri, n);
    pass2_kernel<<<dim3(n / 64, 8), 256, 0, stream>>>(qh, ql, kh, kl, msgsT,
                                                      rowm, rowri, aggO, attn, n);
    aggln_kernel<false><<<n / 16, 256, 0, stream>>>(h2, aggO, aggM, aggL,
                                                    Wa, ba, lg, lb, hOut, n);
}

// Round 4
// 441.549 us; speedup vs baseline: 1.6070x; 1.0883x over previous
//
#include <hip/hip_runtime.h>

constexpr int H = 256, MSGC = 64;
constexpr float LN_EPS = 1e-5f;
// fold 1/sqrt(16) AND log2(e) into q so softmax exps are single v_exp_f32 (exp2)
constexpr float QSCALE = 0.25f * 1.4426950408889634f;

typedef __attribute__((ext_vector_type(8))) short bf16x8;
typedef __attribute__((ext_vector_type(4))) float f32x4;

__device__ inline ushort f2bf(float x) {
    union { float f; unsigned u; } v; v.f = x;
    unsigned r = v.u + 0x7fffu + ((v.u >> 16) & 1u);
    return (ushort)(r >> 16);
}
__device__ inline float bf2f(ushort h) {
    union { unsigned u; float f; } v; v.u = ((unsigned)h) << 16;
    return v.f;
}

// ---------------- prep: transpose weights once (coalesced B-operands) ----------------
// blocks 0..95: WT[k][96] packed cols {0-63 msg, 64-79 key, 80-95 qry}
// blocks 96..351: WaT[k][256]
__global__ __launch_bounds__(320) void prep_kernel(
    const float* __restrict__ Wm, const float* __restrict__ Wk,
    const float* __restrict__ Wq, const float* __restrict__ Wa,
    float* __restrict__ WT, float* __restrict__ WaT)
{
    const int t = threadIdx.x, b = blockIdx.x;
    if (b < 96) {
        if (t < 256) {
            const float* src = (b < 64) ? (Wm + (size_t)b * H)
                             : (b < 80) ? (Wk + (size_t)(b - 64) * H)
                                        : (Wq + (size_t)(b - 80) * H);
            WT[(size_t)t * 96 + b] = src[t];
        }
    } else {
        const int o = b - 96;          // output col 0..255
        WaT[(size_t)t * 256 + o] = Wa[(size_t)o * 320 + t];
    }
}

// ---------------- proj: split-bf16 q/k (q pre-scaled) and fragment-packed bf16 msgsF ----------------
__global__ __launch_bounds__(128) void proj_kernel(
    const float* __restrict__ h, const float* __restrict__ WT,
    const float* __restrict__ bm, const float* __restrict__ bk, const float* __restrict__ bq,
    ushort* __restrict__ msgsF, ushort* __restrict__ kh, ushort* __restrict__ kl,
    ushort* __restrict__ qh, ushort* __restrict__ ql, int n)
{
    __shared__ float hl[16 * H];
    const int t = threadIdx.x;
    const int r0 = blockIdx.x * 16;
    const float4* src = (const float4*)(h + (size_t)r0 * H);
    float4* dst = (float4*)hl;
#pragma unroll
    for (int u = 0; u < 8; ++u) dst[t + 128 * u] = src[t + 128 * u];
    __syncthreads();
    if (t < 96) {
        float acc[16];
#pragma unroll
        for (int r = 0; r < 16; ++r) acc[r] = 0.f;
        const float4* h4 = (const float4*)hl;
        for (int k4 = 0; k4 < 64; ++k4) {
            const float* wp = WT + (size_t)(k4 * 4) * 96 + t;   // coalesced across t
            float w0 = wp[0], w1 = wp[96], w2 = wp[192], w3 = wp[288];
#pragma unroll
            for (int r = 0; r < 16; ++r) {
                float4 hv = h4[r * 64 + k4];   // uniform address -> LDS broadcast
                acc[r] += hv.x * w0 + hv.y * w1 + hv.z * w2 + hv.w * w3;
            }
        }
        if (t < 64) {
            float bb = bm[t];
#pragma unroll
            for (int r = 0; r < 16; ++r) {
                const int j = r0 + r;
                const size_t idx = ((size_t)(j >> 5) * 4 + (t >> 4)) * 512
                                 + ((j >> 3) & 3) * 128 + (t & 15) * 8 + (j & 7);
                msgsF[idx] = f2bf(acc[r] + bb);
            }
        } else if (t < 80) {
            const int cc = t - 64; float bb = bk[cc];
#pragma unroll
            for (int r = 0; r < 16; ++r) {
                float v = acc[r] + bb;
                ushort hi = f2bf(v);
                kh[(size_t)(r0 + r) * 16 + cc] = hi;
                kl[(size_t)(r0 + r) * 16 + cc] = f2bf(v - bf2f(hi));
            }
        } else {
            const int cc = t - 80; float bb = bq[cc];
#pragma unroll
            for (int r = 0; r < 16; ++r) {
                float v = QSCALE * (acc[r] + bb);
                ushort hi = f2bf(v);
                qh[(size_t)(r0 + r) * 16 + cc] = hi;
                ql[(size_t)(r0 + r) * 16 + cc] = f2bf(v - bf2f(hi));
            }
        }
    }
}

// ---------------- flash1: round-1 fused online-softmax attention (no attn write) ----------------
__global__ __launch_bounds__(256) void flash1_kernel(
    const ushort* __restrict__ qh, const ushort* __restrict__ ql,
    const ushort* __restrict__ kh, const ushort* __restrict__ kl,
    const ushort* __restrict__ msgsF,
    float* __restrict__ aggO, float* __restrict__ aggM, float* __restrict__ aggL, int n)
{
    __shared__ float P[64 * 64];           // 16 KB, XOR-swizzled; waves own disjoint 16-row bands
    const int t = threadIdx.x, lane = t & 63, w = t >> 6;
    const int g = lane >> 4, c = lane & 15;
    const int i0 = blockIdx.x * 64;
    bf16x8 zer = {0,0,0,0,0,0,0,0};
    f32x4 z4 = {0.f, 0.f, 0.f, 0.f};
    const ushort* qsrc = (g < 2) ? qh : ql;
    bf16x8 a1 = *(const bf16x8*)(qsrc + (size_t)(i0 + w * 16 + c) * 16 + 8 * (g & 1));
    bf16x8 a2 = (g < 2) ? a1 : zer;
    float m[4] = {-1e30f, -1e30f, -1e30f, -1e30f}, l[4] = {0.f, 0.f, 0.f, 0.f};
    f32x4 accv[4] = {z4, z4, z4, z4};
    const int nj = n / 8, jb = blockIdx.y * nj;
    for (int jt = 0; jt < nj / 64; ++jt) {
        const int j0 = jb + jt * 64;
        f32x4 pd[4];
#pragma unroll
        for (int js = 0; js < 4; ++js) {
            const int j = j0 + js * 16 + c;
            bf16x8 b1 = *(const bf16x8*)(kh + (size_t)j * 16 + 8 * (g & 1));
            bf16x8 b2 = (g < 2) ? *(const bf16x8*)(kl + (size_t)j * 16 + 8 * g) : zer;
            pd[js] = __builtin_amdgcn_mfma_f32_16x16x32_bf16(a1, b1, z4, 0, 0, 0);
            pd[js] = __builtin_amdgcn_mfma_f32_16x16x32_bf16(a2, b2, pd[js], 0, 0, 0);
        }
        float sc[4];
#pragma unroll
        for (int r = 0; r < 4; ++r) {
            float tm = fmaxf(fmaxf(pd[0][r], pd[1][r]), fmaxf(pd[2][r], pd[3][r]));
#pragma unroll
            for (int d2 = 1; d2 < 16; d2 <<= 1) tm = fmaxf(tm, __shfl_xor(tm, d2, 64));
            float nm = fmaxf(m[r], tm);
            sc[r] = exp2f(m[r] - nm);
            m[r] = nm;
            l[r] *= sc[r];
        }
#pragma unroll
        for (int mt = 0; mt < 4; ++mt) {
            accv[mt][0] *= sc[0]; accv[mt][1] *= sc[1];
            accv[mt][2] *= sc[2]; accv[mt][3] *= sc[3];
        }
#pragma unroll
        for (int js = 0; js < 4; ++js) {
#pragma unroll
            for (int r = 0; r < 4; ++r) {
                const int row = w * 16 + g * 4 + r;
                float p = exp2f(pd[js][r] - m[r]);
                l[r] += p;
                const int col = js * 16 + c;
                P[row * 64 + (col ^ ((row & 7) << 2))] = p;
            }
        }
        // PV: each wave consumes only its own band -> no barriers anywhere
#pragma unroll
        for (int ks = 0; ks < 2; ++ks) {
            const int arow = w * 16 + c;
            const int sw = (arow & 7) << 2;
            const int colb = ks * 32 + 8 * g;
            float4 f0 = *(const float4*)&P[arow * 64 + ((colb) ^ sw)];
            float4 f1 = *(const float4*)&P[arow * 64 + ((colb + 4) ^ sw)];
            bf16x8 af;
            af[0] = (short)f2bf(f0.x); af[1] = (short)f2bf(f0.y);
            af[2] = (short)f2bf(f0.z); af[3] = (short)f2bf(f0.w);
            af[4] = (short)f2bf(f1.x); af[5] = (short)f2bf(f1.y);
            af[6] = (short)f2bf(f1.z); af[7] = (short)f2bf(f1.w);
            const size_t mbase = ((size_t)(j0 >> 5) + ks) * 4;
#pragma unroll
            for (int mt = 0; mt < 4; ++mt) {
                bf16x8 bfr = *((const bf16x8*)(msgsF + (mbase + mt) * 512) + lane);  // contiguous 1KB/wave
                accv[mt] = __builtin_amdgcn_mfma_f32_16x16x32_bf16(af, bfr, accv[mt], 0, 0, 0);
            }
        }
    }
#pragma unroll
    for (int r = 0; r < 4; ++r)
#pragma unroll
        for (int d2 = 1; d2 < 16; d2 <<= 1) l[r] += __shfl_xor(l[r], d2, 64);
#pragma unroll
    for (int mt = 0; mt < 4; ++mt)
#pragma unroll
        for (int r = 0; r < 4; ++r)
            aggO[((size_t)blockIdx.y * n + i0 + w * 16 + g * 4 + r) * MSGC + mt * 16 + c] = accv[mt][r];
    if (c == 0) {
#pragma unroll
        for (int r = 0; r < 4; ++r) {
            aggM[(size_t)blockIdx.y * n + i0 + w * 16 + g * 4 + r] = m[r];
            aggL[(size_t)blockIdx.y * n + i0 + w * 16 + g * 4 + r] = l[r];
        }
    }
}

// ---------------- stats (round 2): max-pass then sum-pass, exp out of dep chain ----------------
__global__ __launch_bounds__(256) void stats_kernel(
    const ushort* __restrict__ qh, const ushort* __restrict__ ql,
    const ushort* __restrict__ kh, const ushort* __restrict__ kl,
    float* __restrict__ rowm_p, float* __restrict__ rowl_p, int n)
{
    const int t = threadIdx.x, lane = t & 63, w = t >> 6;
    const int g = lane >> 4, c = lane & 15;
    const int iq = blockIdx.x * 64 + w * 16 + c;
    bf16x8 zer = {0,0,0,0,0,0,0,0};
    f32x4 z4 = {0.f, 0.f, 0.f, 0.f};
    const ushort* qsrc = (g < 2) ? qh : ql;
    bf16x8 a1 = *(const bf16x8*)(qsrc + (size_t)iq * 16 + 8 * (g & 1));
    bf16x8 a2 = (g < 2) ? a1 : zer;
    const int nj = n / 8, jb = blockIdx.y * nj;
    float m[4] = {-1e30f, -1e30f, -1e30f, -1e30f};
    for (int js = 0; js < nj; js += 16) {
        const int j = jb + js + c;
        bf16x8 b1 = *(const bf16x8*)(kh + (size_t)j * 16 + 8 * (g & 1));
        bf16x8 b2 = (g < 2) ? *(const bf16x8*)(kl + (size_t)j * 16 + 8 * g) : zer;
        f32x4 d = __builtin_amdgcn_mfma_f32_16x16x32_bf16(a1, b1, z4, 0, 0, 0);
        d = __builtin_amdgcn_mfma_f32_16x16x32_bf16(a2, b2, d, 0, 0, 0);
#pragma unroll
        for (int r = 0; r < 4; ++r) m[r] = fmaxf(m[r], d[r]);
    }
#pragma unroll
    for (int r = 0; r < 4; ++r)
#pragma unroll
        for (int d2 = 1; d2 < 16; d2 <<= 1) m[r] = fmaxf(m[r], __shfl_xor(m[r], d2, 64));
    float l[4] = {0.f, 0.f, 0.f, 0.f};
    for (int js = 0; js < nj; js += 16) {
        const int j = jb + js + c;
        bf16x8 b1 = *(const bf16x8*)(kh + (size_t)j * 16 + 8 * (g & 1));
        bf16x8 b2 = (g < 2) ? *(const bf16x8*)(kl + (size_t)j * 16 + 8 * g) : zer;
        f32x4 d = __builtin_amdgcn_mfma_f32_16x16x32_bf16(a1, b1, z4, 0, 0, 0);
        d = __builtin_amdgcn_mfma_f32_16x16x32_bf16(a2, b2, d, 0, 0, 0);
#pragma unroll
        for (int r = 0; r < 4; ++r) l[r] += exp2f(d[r] - m[r]);
    }
#pragma unroll
    for (int r = 0; r < 4; ++r)
#pragma unroll
        for (int d2 = 1; d2 < 16; d2 <<= 1) l[r] += __shfl_xor(l[r], d2, 64);
    if (c == 0) {
        const int q0 = blockIdx.x * 64 + w * 16 + g * 4;
#pragma unroll
        for (int r = 0; r < 4; ++r) {
            rowm_p[(size_t)blockIdx.y * n + q0 + r] = m[r];
            rowl_p[(size_t)blockIdx.y * n + q0 + r] = l[r];
        }
    }
}

__global__ __launch_bounds__(256) void combine_kernel(
    const float* __restrict__ rowm_p, const float* __restrict__ rowl_p,
    float* __restrict__ rowm, float* __restrict__ rowrinv, int n)
{
    const int q = blockIdx.x * 256 + threadIdx.x;
    float m = -1e30f;
#pragma unroll
    for (int p = 0; p < 8; ++p) m = fmaxf(m, rowm_p[(size_t)p * n + q]);
    float l = 0.f;
#pragma unroll
    for (int p = 0; p < 8; ++p) l += rowl_p[(size_t)p * n + q] * exp2f(rowm_p[(size_t)p * n + q] - m);
    rowm[q] = m;
    rowrinv[q] = 1.f / l;
}

// ---------------- pass2 (round 2): normalized P -> attn write + PV ----------------
__global__ __launch_bounds__(256) void pass2_kernel(
    const ushort* __restrict__ qh, const ushort* __restrict__ ql,
    const ushort* __restrict__ kh, const ushort* __restrict__ kl,
    const ushort* __restrict__ msgsF, const float* __restrict__ rowm,
    const float* __restrict__ rowrinv, float* __restrict__ aggO,
    float* __restrict__ attn, int n)
{
    __shared__ float P[64 * 128];          // 32 KB
    const int t = threadIdx.x, lane = t & 63, w = t >> 6;
    const int g = lane >> 4, c = lane & 15;
    const int i0 = blockIdx.x * 64;
    bf16x8 zer = {0,0,0,0,0,0,0,0};
    f32x4 z4 = {0.f, 0.f, 0.f, 0.f};
    const ushort* qsrc = (g < 2) ? qh : ql;
    bf16x8 a1 = *(const bf16x8*)(qsrc + (size_t)(i0 + w * 16 + c) * 16 + 8 * (g & 1));
    bf16x8 a2 = (g < 2) ? a1 : zer;
    float m_r[4], rinv_r[4];
#pragma unroll
    for (int r = 0; r < 4; ++r) {
        const int q = i0 + w * 16 + g * 4 + r;
        m_r[r] = rowm[q];
        rinv_r[r] = rowrinv[q];
    }
    f32x4 accv[4] = {z4, z4, z4, z4};
    const int nj = n / 8, jb = blockIdx.y * nj;
    for (int jt = 0; jt < nj / 128; ++jt) {
        const int j0 = jb + jt * 128;
#pragma unroll
        for (int js = 0; js < 8; ++js) {
            const int j = j0 + js * 16 + c;
            bf16x8 b1 = *(const bf16x8*)(kh + (size_t)j * 16 + 8 * (g & 1));
            bf16x8 b2 = (g < 2) ? *(const bf16x8*)(kl + (size_t)j * 16 + 8 * g) : zer;
            f32x4 d = __builtin_amdgcn_mfma_f32_16x16x32_bf16(a1, b1, z4, 0, 0, 0);
            d = __builtin_amdgcn_mfma_f32_16x16x32_bf16(a2, b2, d, 0, 0, 0);
#pragma unroll
            for (int r = 0; r < 4; ++r) {
                const int row = w * 16 + g * 4 + r;
                const float p = exp2f(d[r] - m_r[r]) * rinv_r[r];
                const int col = js * 16 + c;
                P[row * 128 + (col ^ ((row & 7) << 2))] = p;
            }
        }
        __syncthreads();
#pragma unroll
        for (int u = 0; u < 8; ++u) {
            const int row = (t >> 5) + u * 8;
            const int colb = (t & 31) * 4;
            float4 v = *(const float4*)&P[row * 128 + (colb ^ ((row & 7) << 2))];
            *(float4*)(attn + (size_t)(i0 + row) * n + j0 + colb) = v;
        }
#pragma unroll
        for (int ks = 0; ks < 4; ++ks) {
            const int arow = w * 16 + c;
            const int sw = (arow & 7) << 2;
            const int colb = ks * 32 + 8 * g;
            float4 f0 = *(const float4*)&P[arow * 128 + ((colb) ^ sw)];
            float4 f1 = *(const float4*)&P[arow * 128 + ((colb + 4) ^ sw)];
            bf16x8 af;
            af[0] = (short)f2bf(f0.x); af[1] = (short)f2bf(f0.y);
            af[2] = (short)f2bf(f0.z); af[3] = (short)f2bf(f0.w);
            af[4] = (short)f2bf(f1.x); af[5] = (short)f2bf(f1.y);
            af[6] = (short)f2bf(f1.z); af[7] = (short)f2bf(f1.w);
            const size_t mbase = ((size_t)(j0 >> 5) + ks) * 4;
#pragma unroll
            for (int mt = 0; mt < 4; ++mt) {
                bf16x8 bfr = *((const bf16x8*)(msgsF + (mbase + mt) * 512) + lane);
                accv[mt] = __builtin_amdgcn_mfma_f32_16x16x32_bf16(af, bfr, accv[mt], 0, 0, 0);
            }
        }
        __syncthreads();
    }
#pragma unroll
    for (int mt = 0; mt < 4; ++mt)
#pragma unroll
        for (int r = 0; r < 4; ++r) {
            const int row = w * 16 + g * 4 + r;
            aggO[((size_t)blockIdx.y * n + i0 + row) * MSGC + mt * 16 + c] = accv[mt][r];
        }
}

// ---------------- aggln: z = [h, agg] @ W_agg.T + b; LayerNorm; ReLU ----------------
// 16 rows/block, thread = 4 rows x 4 cols; A = LDS broadcast b128, B = coalesced WaT
template <bool FLASH>
__global__ __launch_bounds__(256) void aggln_kernel(
    const float* __restrict__ h, const float* __restrict__ aggO,
    const float* __restrict__ aggM, const float* __restrict__ aggL,
    const float* __restrict__ WaT, const float* __restrict__ ba,
    const float* __restrict__ g, const float* __restrict__ b,
    float* __restrict__ hout, int n)
{
    constexpr int CST = 324;               // row stride (floats), 16B-aligned
    __shared__ float comb[16 * CST];
    __shared__ float mm[16][8], ll[16][8], wgt[16][8];
    const int t = threadIdx.x;
    const int r0 = blockIdx.x * 16;
    const float4* hsrc = (const float4*)(h + (size_t)r0 * H);
#pragma unroll
    for (int u = 0; u < 4; ++u) {
        const int idx = t + 256 * u;
        const int r = idx >> 6, kk = idx & 63;
        *(float4*)(comb + r * CST + kk * 4) = hsrc[idx];
    }
    if (FLASH) {
        if (t < 128) {
            const int r = t >> 3, p = t & 7;
            mm[r][p] = aggM[(size_t)p * n + r0 + r];
            ll[r][p] = aggL[(size_t)p * n + r0 + r];
        }
        __syncthreads();
        if (t < 16) {
            float M = mm[t][0];
#pragma unroll
            for (int p = 1; p < 8; ++p) M = fmaxf(M, mm[t][p]);
            float L = 0.f;
#pragma unroll
            for (int p = 0; p < 8; ++p) L += ll[t][p] * exp2f(mm[t][p] - M);
            const float inv = 1.f / L;
#pragma unroll
            for (int p = 0; p < 8; ++p) wgt[t][p] = exp2f(mm[t][p] - M) * inv;
        }
        __syncthreads();
    }
    for (int idx = t; idx < 16 * 64; idx += 256) {
        const int r = idx >> 6, cc = idx & 63;
        float s = 0.f;
#pragma unroll
        for (int p = 0; p < 8; ++p) {
            float v = aggO[(size_t)p * n * MSGC + (size_t)(r0 + r) * MSGC + cc];
            s += FLASH ? v * wgt[r][p] : v;
        }
        comb[r * CST + 256 + cc] = s;
    }
    __syncthreads();
    const int tr = t >> 6, tc = t & 63;    // wave tr owns rows tr*4..tr*4+3
    f32x4 acc[4] = {{0,0,0,0},{0,0,0,0},{0,0,0,0},{0,0,0,0}};
    for (int k4 = 0; k4 < 80; ++k4) {
        const float* bp = WaT + (size_t)(k4 * 4) * 256 + tc * 4;
        f32x4 b0 = *(const f32x4*)(bp);
        f32x4 b1 = *(const f32x4*)(bp + 256);
        f32x4 b2 = *(const f32x4*)(bp + 512);
        f32x4 b3 = *(const f32x4*)(bp + 768);
#pragma unroll
        for (int r = 0; r < 4; ++r) {
            f32x4 av = *(const f32x4*)(comb + (tr * 4 + r) * CST + k4 * 4);   // broadcast
            acc[r] += av.x * b0 + av.y * b1 + av.z * b2 + av.w * b3;
        }
    }
    f32x4 bav = *(const f32x4*)(ba + tc * 4);
    f32x4 gv = *(const f32x4*)(g + tc * 4);
    f32x4 bv = *(const f32x4*)(b + tc * 4);
#pragma unroll
    for (int r = 0; r < 4; ++r) {
        acc[r] += bav;
        float s1 = acc[r][0] + acc[r][1] + acc[r][2] + acc[r][3];
        float s2 = acc[r][0]*acc[r][0] + acc[r][1]*acc[r][1]
                 + acc[r][2]*acc[r][2] + acc[r][3]*acc[r][3];
#pragma unroll
        for (int d = 1; d < 64; d <<= 1) { s1 += __shfl_xor(s1, d, 64); s2 += __shfl_xor(s2, d, 64); }
        const float mu = s1 * (1.f / 256.f);
        const float var = s2 * (1.f / 256.f) - mu * mu;
        const float rs = rsqrtf(var + LN_EPS);
        f32x4 o = (acc[r] - mu) * rs * gv + bv;
        o[0] = fmaxf(o[0], 0.f); o[1] = fmaxf(o[1], 0.f);
        o[2] = fmaxf(o[2], 0.f); o[3] = fmaxf(o[3], 0.f);
        *(f32x4*)(hout + (size_t)(r0 + tr * 4 + r) * H + tc * 4) = o;
    }
}

extern "C" void kernel_launch(void* const* d_in, const int* in_sizes, int n_in,
                              void* d_out, int out_size, void* d_ws, size_t ws_size,
                              hipStream_t stream)
{
    const float* hs = (const float*)d_in[0];
    const float* Wm = (const float*)d_in[1];
    const float* bm = (const float*)d_in[2];
    const float* Wk = (const float*)d_in[3];
    const float* bk = (const float*)d_in[4];
    const float* Wq = (const float*)d_in[5];
    const float* bq = (const float*)d_in[6];
    const float* Wa = (const float*)d_in[7];
    const float* ba = (const float*)d_in[8];
    const float* lg = (const float*)d_in[9];
    const float* lb = (const float*)d_in[10];
    const int n = in_sizes[0] / H;         // 8192

    char* wp = (char*)d_ws;
    auto alloc = [&](size_t bytes) { void* p = (void*)wp; wp += (bytes + 255) & ~(size_t)255; return p; };
    float*  h2     = (float*)alloc((size_t)n * H * 4);
    ushort* qh     = (ushort*)alloc((size_t)n * 16 * 2);
    ushort* ql     = (ushort*)alloc((size_t)n * 16 * 2);
    ushort* kh     = (ushort*)alloc((size_t)n * 16 * 2);
    ushort* kl     = (ushort*)alloc((size_t)n * 16 * 2);
    ushort* msgsF  = (ushort*)alloc((size_t)MSGC * n * 2);
    float*  rowm_p = (float*)alloc((size_t)8 * n * 4);
    float*  rowl_p = (float*)alloc((size_t)8 * n * 4);
    float*  rowm   = (float*)alloc((size_t)n * 4);
    float*  rowri  = (float*)alloc((size_t)n * 4);
    float*  aggO   = (float*)alloc((size_t)8 * n * MSGC * 4);
    float*  aggM   = (float*)alloc((size_t)8 * n * 4);
    float*  aggL   = (float*)alloc((size_t)8 * n * 4);
    float*  WT     = (float*)alloc((size_t)256 * 96 * 4);
    float*  WaT    = (float*)alloc((size_t)320 * 256 * 4);

    float* hOut = (float*)d_out;
    float* attn = hOut + (size_t)n * H;

    prep_kernel<<<352, 320, 0, stream>>>(Wm, Wk, Wq, Wa, WT, WaT);

    // round 1: fused flash (no stats pass, no attn write)
    proj_kernel<<<n / 16, 128, 0, stream>>>(hs, WT, bm, bk, bq, msgsF, kh, kl, qh, ql, n);
    flash1_kernel<<<dim3(n / 64, 8), 256, 0, stream>>>(qh, ql, kh, kl, msgsF,
                                                       aggO, aggM, aggL, n);
    aggln_kernel<true><<<n / 16, 256, 0, stream>>>(hs, aggO, aggM, aggL,
                                                   WaT, ba, lg, lb, h2, n);
    // round 2: stats (two-pass) + pass2 (writes normalized attn)
    proj_kernel<<<n / 16, 128, 0, stream>>>(h2, WT, bm, bk, bq, msgsF, kh, kl, qh, ql, n);
    stats_kernel<<<dim3(n / 64, 8), 256, 0, stream>>>(qh, ql, kh, kl, rowm_p, rowl_p, n);
    combine_kernel<<<n / 256, 256, 0, stream>>>(rowm_p, rowl_p, rowm, rowri, n);
    pass2_kernel<<<dim3(n / 64, 8), 256, 0, stream>>>(qh, ql, kh, kl, msgsF,
                                                      rowm, rowri, aggO, attn, n);
    aggln_kernel<false><<<n / 16, 256, 0, stream>>>(h2, aggO, aggM, aggL,
                                                    WaT, ba, lg, lb, hOut, n);
}

// Round 5
// 307.873 us; speedup vs baseline: 2.3047x; 1.4342x over previous
//
#include <hip/hip_runtime.h>

constexpr int H = 256, MSGC = 64;
constexpr float LN_EPS = 1e-5f;
// fold 1/sqrt(16) AND log2(e) into q so softmax exps are single v_exp_f32 (exp2)
constexpr float QSCALE = 0.25f * 1.4426950408889634f;

typedef __attribute__((ext_vector_type(8))) short bf16x8;
typedef __attribute__((ext_vector_type(4))) float f32x4;

__device__ inline ushort f2bf(float x) {
    union { float f; unsigned u; } v; v.f = x;
    unsigned r = v.u + 0x7fffu + ((v.u >> 16) & 1u);
    return (ushort)(r >> 16);
}
__device__ inline float bf2f(ushort h) {
    union { unsigned u; float f; } v; v.u = ((unsigned)h) << 16;
    return v.f;
}
// pack 8 f32 -> bf16x8 via v_cvt_pk_bf16_f32 (RNE), 4 instructions
__device__ inline bf16x8 pack_bf16x8(float4 f0, float4 f1) {
    union { unsigned u[4]; bf16x8 v; } cv;
    asm("v_cvt_pk_bf16_f32 %0, %1, %2" : "=v"(cv.u[0]) : "v"(f0.x), "v"(f0.y));
    asm("v_cvt_pk_bf16_f32 %0, %1, %2" : "=v"(cv.u[1]) : "v"(f0.z), "v"(f0.w));
    asm("v_cvt_pk_bf16_f32 %0, %1, %2" : "=v"(cv.u[2]) : "v"(f1.x), "v"(f1.y));
    asm("v_cvt_pk_bf16_f32 %0, %1, %2" : "=v"(cv.u[3]) : "v"(f1.z), "v"(f1.w));
    return cv.v;
}

// ---------------- prep: transpose weights once (coalesced B-operands) ----------------
__global__ __launch_bounds__(320) void prep_kernel(
    const float* __restrict__ Wm, const float* __restrict__ Wk,
    const float* __restrict__ Wq, const float* __restrict__ Wa,
    float* __restrict__ WT, float* __restrict__ WaT)
{
    const int t = threadIdx.x, b = blockIdx.x;
    if (b < 96) {
        if (t < 256) {
            const float* src = (b < 64) ? (Wm + (size_t)b * H)
                             : (b < 80) ? (Wk + (size_t)(b - 64) * H)
                                        : (Wq + (size_t)(b - 80) * H);
            WT[(size_t)t * 96 + b] = src[t];
        }
    } else {
        const int o = b - 96;
        WaT[(size_t)t * 256 + o] = Wa[(size_t)o * 320 + t];
    }
}

// ---------------- proj: 8 rows/block (2x waves), split-bf16 q/k, fragment-packed msgsF ----------------
__global__ __launch_bounds__(128) void proj_kernel(
    const float* __restrict__ h, const float* __restrict__ WT,
    const float* __restrict__ bm, const float* __restrict__ bk, const float* __restrict__ bq,
    ushort* __restrict__ msgsF, ushort* __restrict__ kh, ushort* __restrict__ kl,
    ushort* __restrict__ qh, ushort* __restrict__ ql, int n)
{
    __shared__ float hl[8 * H];
    const int t = threadIdx.x;
    const int r0 = blockIdx.x * 8;
    const float4* src = (const float4*)(h + (size_t)r0 * H);
    float4* dst = (float4*)hl;
#pragma unroll
    for (int u = 0; u < 4; ++u) dst[t + 128 * u] = src[t + 128 * u];
    __syncthreads();
    if (t < 96) {
        float acc[8];
#pragma unroll
        for (int r = 0; r < 8; ++r) acc[r] = 0.f;
        const float4* h4 = (const float4*)hl;
        for (int k4 = 0; k4 < 64; ++k4) {
            const float* wp = WT + (size_t)(k4 * 4) * 96 + t;   // coalesced across t
            float w0 = wp[0], w1 = wp[96], w2 = wp[192], w3 = wp[288];
#pragma unroll
            for (int r = 0; r < 8; ++r) {
                float4 hv = h4[r * 64 + k4];   // uniform address -> LDS broadcast
                acc[r] += hv.x * w0 + hv.y * w1 + hv.z * w2 + hv.w * w3;
            }
        }
        if (t < 64) {
            float bb = bm[t];
#pragma unroll
            for (int r = 0; r < 8; ++r) {
                const int j = r0 + r;
                const size_t idx = ((size_t)(j >> 5) * 4 + (t >> 4)) * 512
                                 + ((j >> 3) & 3) * 128 + (t & 15) * 8 + (j & 7);
                msgsF[idx] = f2bf(acc[r] + bb);
            }
        } else if (t < 80) {
            const int cc = t - 64; float bb = bk[cc];
#pragma unroll
            for (int r = 0; r < 8; ++r) {
                float v = acc[r] + bb;
                ushort hi = f2bf(v);
                kh[(size_t)(r0 + r) * 16 + cc] = hi;
                kl[(size_t)(r0 + r) * 16 + cc] = f2bf(v - bf2f(hi));
            }
        } else {
            const int cc = t - 80; float bb = bq[cc];
#pragma unroll
            for (int r = 0; r < 8; ++r) {
                float v = QSCALE * (acc[r] + bb);
                ushort hi = f2bf(v);
                qh[(size_t)(r0 + r) * 16 + cc] = hi;
                ql[(size_t)(r0 + r) * 16 + cc] = f2bf(v - bf2f(hi));
            }
        }
    }
}

// ---------------- flash1: round-1 fused online-softmax attention, barrier-free ----------------
__global__ __launch_bounds__(256) void flash1_kernel(
    const ushort* __restrict__ qh, const ushort* __restrict__ ql,
    const ushort* __restrict__ kh, const ushort* __restrict__ kl,
    const ushort* __restrict__ msgsF,
    float* __restrict__ aggO, float* __restrict__ aggM, float* __restrict__ aggL, int n)
{
    __shared__ float P[64 * 64];           // 16 KB, XOR-swizzled; waves own disjoint 16-row bands
    const int t = threadIdx.x, lane = t & 63, w = t >> 6;
    const int g = lane >> 4, c = lane & 15;
    const int i0 = blockIdx.x * 64;
    bf16x8 zer = {0,0,0,0,0,0,0,0};
    f32x4 z4 = {0.f, 0.f, 0.f, 0.f};
    const ushort* qsrc = (g < 2) ? qh : ql;
    bf16x8 a1 = *(const bf16x8*)(qsrc + (size_t)(i0 + w * 16 + c) * 16 + 8 * (g & 1));
    bf16x8 a2 = (g < 2) ? a1 : zer;
    float m[4] = {-1e30f, -1e30f, -1e30f, -1e30f}, l[4] = {0.f, 0.f, 0.f, 0.f};
    f32x4 accv[4] = {z4, z4, z4, z4};
    const int nj = n / 8, jb = blockIdx.y * nj;
    for (int jt = 0; jt < nj / 64; ++jt) {
        const int j0 = jb + jt * 64;
        // stage all K fragments for this 64-col tile (batched loads, single wait)
        bf16x8 b1s[4], b2s[4];
#pragma unroll
        for (int js = 0; js < 4; ++js) {
            const int j = j0 + js * 16 + c;
            b1s[js] = *(const bf16x8*)(kh + (size_t)j * 16 + 8 * (g & 1));
            b2s[js] = (g < 2) ? *(const bf16x8*)(kl + (size_t)j * 16 + 8 * g) : zer;
        }
        f32x4 pd[4];
#pragma unroll
        for (int js = 0; js < 4; ++js) {
            pd[js] = __builtin_amdgcn_mfma_f32_16x16x32_bf16(a1, b1s[js], z4, 0, 0, 0);
            pd[js] = __builtin_amdgcn_mfma_f32_16x16x32_bf16(a2, b2s[js], pd[js], 0, 0, 0);
        }
        float sc[4];
#pragma unroll
        for (int r = 0; r < 4; ++r) {
            float tm = fmaxf(fmaxf(pd[0][r], pd[1][r]), fmaxf(pd[2][r], pd[3][r]));
#pragma unroll
            for (int d2 = 1; d2 < 16; d2 <<= 1) tm = fmaxf(tm, __shfl_xor(tm, d2, 64));
            float nm = fmaxf(m[r], tm);
            sc[r] = exp2f(m[r] - nm);
            m[r] = nm;
            l[r] *= sc[r];
        }
#pragma unroll
        for (int mt = 0; mt < 4; ++mt) {
            accv[mt][0] *= sc[0]; accv[mt][1] *= sc[1];
            accv[mt][2] *= sc[2]; accv[mt][3] *= sc[3];
        }
#pragma unroll
        for (int js = 0; js < 4; ++js) {
#pragma unroll
            for (int r = 0; r < 4; ++r) {
                const int row = w * 16 + g * 4 + r;
                float p = exp2f(pd[js][r] - m[r]);
                l[r] += p;
                const int col = js * 16 + c;
                P[row * 64 + (col ^ ((row & 7) << 2))] = p;
            }
        }
        // PV: own-band only, no barriers
#pragma unroll
        for (int ks = 0; ks < 2; ++ks) {
            const int arow = w * 16 + c;
            const int sw = (arow & 7) << 2;
            const int colb = ks * 32 + 8 * g;
            float4 f0 = *(const float4*)&P[arow * 64 + ((colb) ^ sw)];
            float4 f1 = *(const float4*)&P[arow * 64 + ((colb + 4) ^ sw)];
            bf16x8 af = pack_bf16x8(f0, f1);
            const size_t mbase = ((size_t)(j0 >> 5) + ks) * 4;
#pragma unroll
            for (int mt = 0; mt < 4; ++mt) {
                bf16x8 bfr = *((const bf16x8*)(msgsF + (mbase + mt) * 512) + lane);
                accv[mt] = __builtin_amdgcn_mfma_f32_16x16x32_bf16(af, bfr, accv[mt], 0, 0, 0);
            }
        }
    }
#pragma unroll
    for (int r = 0; r < 4; ++r)
#pragma unroll
        for (int d2 = 1; d2 < 16; d2 <<= 1) l[r] += __shfl_xor(l[r], d2, 64);
#pragma unroll
    for (int mt = 0; mt < 4; ++mt)
#pragma unroll
        for (int r = 0; r < 4; ++r)
            aggO[((size_t)blockIdx.y * n + i0 + w * 16 + g * 4 + r) * MSGC + mt * 16 + c] = accv[mt][r];
    if (c == 0) {
#pragma unroll
        for (int r = 0; r < 4; ++r) {
            aggM[(size_t)blockIdx.y * n + i0 + w * 16 + g * 4 + r] = m[r];
            aggL[(size_t)blockIdx.y * n + i0 + w * 16 + g * 4 + r] = l[r];
        }
    }
}

// ---------------- stats (round 2): single-pass online (m,l), batched loads ----------------
__global__ __launch_bounds__(256) void stats_kernel(
    const ushort* __restrict__ qh, const ushort* __restrict__ ql,
    const ushort* __restrict__ kh, const ushort* __restrict__ kl,
    float* __restrict__ rowm_p, float* __restrict__ rowl_p, int n)
{
    const int t = threadIdx.x, lane = t & 63, w = t >> 6;
    const int g = lane >> 4, c = lane & 15;
    const int iq = blockIdx.x * 64 + w * 16 + c;
    bf16x8 zer = {0,0,0,0,0,0,0,0};
    f32x4 z4 = {0.f, 0.f, 0.f, 0.f};
    const ushort* qsrc = (g < 2) ? qh : ql;
    bf16x8 a1 = *(const bf16x8*)(qsrc + (size_t)iq * 16 + 8 * (g & 1));
    bf16x8 a2 = (g < 2) ? a1 : zer;
    const int nj = n / 8, jb = blockIdx.y * nj;
    float m[4] = {-1e30f, -1e30f, -1e30f, -1e30f}, l[4] = {0.f, 0.f, 0.f, 0.f};
    for (int jt = 0; jt < nj / 64; ++jt) {
        const int j0 = jb + jt * 64;
        bf16x8 b1s[4], b2s[4];
#pragma unroll
        for (int js = 0; js < 4; ++js) {
            const int j = j0 + js * 16 + c;
            b1s[js] = *(const bf16x8*)(kh + (size_t)j * 16 + 8 * (g & 1));
            b2s[js] = (g < 2) ? *(const bf16x8*)(kl + (size_t)j * 16 + 8 * g) : zer;
        }
        f32x4 pd[4];
#pragma unroll
        for (int js = 0; js < 4; ++js) {
            pd[js] = __builtin_amdgcn_mfma_f32_16x16x32_bf16(a1, b1s[js], z4, 0, 0, 0);
            pd[js] = __builtin_amdgcn_mfma_f32_16x16x32_bf16(a2, b2s[js], pd[js], 0, 0, 0);
        }
#pragma unroll
        for (int r = 0; r < 4; ++r) {
            float tm = fmaxf(fmaxf(pd[0][r], pd[1][r]), fmaxf(pd[2][r], pd[3][r]));
#pragma unroll
            for (int d2 = 1; d2 < 16; d2 <<= 1) tm = fmaxf(tm, __shfl_xor(tm, d2, 64));
            float nm = fmaxf(m[r], tm);
            float sc = exp2f(m[r] - nm);
            m[r] = nm;
            l[r] = l[r] * sc + exp2f(pd[0][r] - nm) + exp2f(pd[1][r] - nm)
                 + exp2f(pd[2][r] - nm) + exp2f(pd[3][r] - nm);
        }
    }
#pragma unroll
    for (int r = 0; r < 4; ++r)
#pragma unroll
        for (int d2 = 1; d2 < 16; d2 <<= 1) l[r] += __shfl_xor(l[r], d2, 64);
    if (c == 0) {
        const int q0 = blockIdx.x * 64 + w * 16 + g * 4;
#pragma unroll
        for (int r = 0; r < 4; ++r) {
            rowm_p[(size_t)blockIdx.y * n + q0 + r] = m[r];
            rowl_p[(size_t)blockIdx.y * n + q0 + r] = l[r];
        }
    }
}

__global__ __launch_bounds__(256) void combine_kernel(
    const float* __restrict__ rowm_p, const float* __restrict__ rowl_p,
    float* __restrict__ rowm, float* __restrict__ rowrinv, int n)
{
    const int q = blockIdx.x * 256 + threadIdx.x;
    float m = -1e30f;
#pragma unroll
    for (int p = 0; p < 8; ++p) m = fmaxf(m, rowm_p[(size_t)p * n + q]);
    float l = 0.f;
#pragma unroll
    for (int p = 0; p < 8; ++p) l += rowl_p[(size_t)p * n + q] * exp2f(rowm_p[(size_t)p * n + q] - m);
    rowm[q] = m;
    rowrinv[q] = 1.f / l;
}

// ---------------- pass2 (round 2): barrier-free; normalized P -> own-band attn write + PV ----------------
__global__ __launch_bounds__(256) void pass2_kernel(
    const ushort* __restrict__ qh, const ushort* __restrict__ ql,
    const ushort* __restrict__ kh, const ushort* __restrict__ kl,
    const ushort* __restrict__ msgsF, const float* __restrict__ rowm,
    const float* __restrict__ rowrinv, float* __restrict__ aggO,
    float* __restrict__ attn, int n)
{
    __shared__ float P[64 * 64];           // 16 KB; waves own disjoint 16-row bands
    const int t = threadIdx.x, lane = t & 63, w = t >> 6;
    const int g = lane >> 4, c = lane & 15;
    const int i0 = blockIdx.x * 64;
    bf16x8 zer = {0,0,0,0,0,0,0,0};
    f32x4 z4 = {0.f, 0.f, 0.f, 0.f};
    const ushort* qsrc = (g < 2) ? qh : ql;
    bf16x8 a1 = *(const bf16x8*)(qsrc + (size_t)(i0 + w * 16 + c) * 16 + 8 * (g & 1));
    bf16x8 a2 = (g < 2) ? a1 : zer;
    float m_r[4], rinv_r[4];
#pragma unroll
    for (int r = 0; r < 4; ++r) {
        const int q = i0 + w * 16 + g * 4 + r;
        m_r[r] = rowm[q];
        rinv_r[r] = rowrinv[q];
    }
    f32x4 accv[4] = {z4, z4, z4, z4};
    const int nj = n / 8, jb = blockIdx.y * nj;
    for (int jt = 0; jt < nj / 64; ++jt) {
        const int j0 = jb + jt * 64;
        bf16x8 b1s[4], b2s[4];
#pragma unroll
        for (int js = 0; js < 4; ++js) {
            const int j = j0 + js * 16 + c;
            b1s[js] = *(const bf16x8*)(kh + (size_t)j * 16 + 8 * (g & 1));
            b2s[js] = (g < 2) ? *(const bf16x8*)(kl + (size_t)j * 16 + 8 * g) : zer;
        }
        f32x4 pd[4];
#pragma unroll
        for (int js = 0; js < 4; ++js) {
            pd[js] = __builtin_amdgcn_mfma_f32_16x16x32_bf16(a1, b1s[js], z4, 0, 0, 0);
            pd[js] = __builtin_amdgcn_mfma_f32_16x16x32_bf16(a2, b2s[js], pd[js], 0, 0, 0);
        }
#pragma unroll
        for (int js = 0; js < 4; ++js) {
#pragma unroll
            for (int r = 0; r < 4; ++r) {
                const int row = w * 16 + g * 4 + r;
                const float p = exp2f(pd[js][r] - m_r[r]) * rinv_r[r];
                const int col = js * 16 + c;
                P[row * 64 + (col ^ ((row & 7) << 2))] = p;
            }
        }
        // attn write: own band (rows w*16..w*16+15), coalesced 256B per row
#pragma unroll
        for (int u = 0; u < 16; ++u) {
            const int row = w * 16 + u;
            const int sw = (row & 7) << 2;
            attn[(size_t)(i0 + row) * n + j0 + lane] = P[row * 64 + (lane ^ sw)];
        }
        // PV: own band
#pragma unroll
        for (int ks = 0; ks < 2; ++ks) {
            const int arow = w * 16 + c;
            const int sw = (arow & 7) << 2;
            const int colb = ks * 32 + 8 * g;
            float4 f0 = *(const float4*)&P[arow * 64 + ((colb) ^ sw)];
            float4 f1 = *(const float4*)&P[arow * 64 + ((colb + 4) ^ sw)];
            bf16x8 af = pack_bf16x8(f0, f1);
            const size_t mbase = ((size_t)(j0 >> 5) + ks) * 4;
#pragma unroll
            for (int mt = 0; mt < 4; ++mt) {
                bf16x8 bfr = *((const bf16x8*)(msgsF + (mbase + mt) * 512) + lane);
                accv[mt] = __builtin_amdgcn_mfma_f32_16x16x32_bf16(af, bfr, accv[mt], 0, 0, 0);
            }
        }
    }
#pragma unroll
    for (int mt = 0; mt < 4; ++mt)
#pragma unroll
        for (int r = 0; r < 4; ++r) {
            const int row = w * 16 + g * 4 + r;
            aggO[((size_t)blockIdx.y * n + i0 + row) * MSGC + mt * 16 + c] = accv[mt][r];
        }
}

// ---------------- aggln: 512 threads, z = [h, agg] @ W_agg.T + b; LayerNorm; ReLU ----------------
template <bool FLASH>
__global__ __launch_bounds__(512) void aggln_kernel(
    const float* __restrict__ h, const float* __restrict__ aggO,
    const float* __restrict__ aggM, const float* __restrict__ aggL,
    const float* __restrict__ WaT, const float* __restrict__ ba,
    const float* __restrict__ g, const float* __restrict__ b,
    float* __restrict__ hout, int n)
{
    constexpr int CST = 324;               // row stride (floats), 16B-aligned
    __shared__ float comb[16 * CST];
    __shared__ float mm[16][8], ll[16][8], wgt[16][8];
    const int t = threadIdx.x;
    const int r0 = blockIdx.x * 16;
    const float4* hsrc = (const float4*)(h + (size_t)r0 * H);
#pragma unroll
    for (int u = 0; u < 2; ++u) {
        const int idx = t + 512 * u;
        const int r = idx >> 6, kk = idx & 63;
        *(float4*)(comb + r * CST + kk * 4) = hsrc[idx];
    }
    if (FLASH) {
        if (t < 128) {
            const int r = t >> 3, p = t & 7;
            mm[r][p] = aggM[(size_t)p * n + r0 + r];
            ll[r][p] = aggL[(size_t)p * n + r0 + r];
        }
        __syncthreads();
        if (t < 16) {
            float M = mm[t][0];
#pragma unroll
            for (int p = 1; p < 8; ++p) M = fmaxf(M, mm[t][p]);
            float L = 0.f;
#pragma unroll
            for (int p = 0; p < 8; ++p) L += ll[t][p] * exp2f(mm[t][p] - M);
            const float inv = 1.f / L;
#pragma unroll
            for (int p = 0; p < 8; ++p) wgt[t][p] = exp2f(mm[t][p] - M) * inv;
        }
        __syncthreads();
    }
#pragma unroll
    for (int u = 0; u < 2; ++u) {
        const int idx = t + 512 * u;
        const int r = idx >> 6, cc = idx & 63;
        float s = 0.f;
#pragma unroll
        for (int p = 0; p < 8; ++p) {
            float v = aggO[(size_t)p * n * MSGC + (size_t)(r0 + r) * MSGC + cc];
            s += FLASH ? v * wgt[r][p] : v;
        }
        comb[r * CST + 256 + cc] = s;
    }
    __syncthreads();
    const int tr = t >> 6, tc = t & 63;    // wave tr owns rows tr*2, tr*2+1
    f32x4 acc[2] = {{0,0,0,0},{0,0,0,0}};
    for (int k4 = 0; k4 < 80; ++k4) {
        const float* bp = WaT + (size_t)(k4 * 4) * 256 + tc * 4;
        f32x4 b0 = *(const f32x4*)(bp);
        f32x4 b1 = *(const f32x4*)(bp + 256);
        f32x4 b2 = *(const f32x4*)(bp + 512);
        f32x4 b3 = *(const f32x4*)(bp + 768);
#pragma unroll
        for (int r = 0; r < 2; ++r) {
            f32x4 av = *(const f32x4*)(comb + (tr * 2 + r) * CST + k4 * 4);   // broadcast
            acc[r] += av.x * b0 + av.y * b1 + av.z * b2 + av.w * b3;
        }
    }
    f32x4 bav = *(const f32x4*)(ba + tc * 4);
    f32x4 gv = *(const f32x4*)(g + tc * 4);
    f32x4 bv = *(const f32x4*)(b + tc * 4);
#pragma unroll
    for (int r = 0; r < 2; ++r) {
        acc[r] += bav;
        float s1 = acc[r][0] + acc[r][1] + acc[r][2] + acc[r][3];
        float s2 = acc[r][0]*acc[r][0] + acc[r][1]*acc[r][1]
                 + acc[r][2]*acc[r][2] + acc[r][3]*acc[r][3];
#pragma unroll
        for (int d = 1; d < 64; d <<= 1) { s1 += __shfl_xor(s1, d, 64); s2 += __shfl_xor(s2, d, 64); }
        const float mu = s1 * (1.f / 256.f);
        const float var = s2 * (1.f / 256.f) - mu * mu;
        const float rs = rsqrtf(var + LN_EPS);
        f32x4 o = (acc[r] - mu) * rs * gv + bv;
        o[0] = fmaxf(o[0], 0.f); o[1] = fmaxf(o[1], 0.f);
        o[2] = fmaxf(o[2], 0.f); o[3] = fmaxf(o[3], 0.f);
        *(f32x4*)(hout + (size_t)(r0 + tr * 2 + r) * H + tc * 4) = o;
    }
}

extern "C" void kernel_launch(void* const* d_in, const int* in_sizes, int n_in,
                              void* d_out, int out_size, void* d_ws, size_t ws_size,
                              hipStream_t stream)
{
    const float* hs = (const float*)d_in[0];
    const float* Wm = (const float*)d_in[1];
    const float* bm = (const float*)d_in[2];
    const float* Wk = (const float*)d_in[3];
    const float* bk = (const float*)d_in[4];
    const float* Wq = (const float*)d_in[5];
    const float* bq = (const float*)d_in[6];
    const float* Wa = (const float*)d_in[7];
    const float* ba = (const float*)d_in[8];
    const float* lg = (const float*)d_in[9];
    const float* lb = (const float*)d_in[10];
    const int n = in_sizes[0] / H;         // 8192

    char* wp = (char*)d_ws;
    auto alloc = [&](size_t bytes) { void* p = (void*)wp; wp += (bytes + 255) & ~(size_t)255; return p; };
    float*  h2     = (float*)alloc((size_t)n * H * 4);
    ushort* qh     = (ushort*)alloc((size_t)n * 16 * 2);
    ushort* ql     = (ushort*)alloc((size_t)n * 16 * 2);
    ushort* kh     = (ushort*)alloc((size_t)n * 16 * 2);
    ushort* kl     = (ushort*)alloc((size_t)n * 16 * 2);
    ushort* msgsF  = (ushort*)alloc((size_t)MSGC * n * 2);
    float*  rowm_p = (float*)alloc((size_t)8 * n * 4);
    float*  rowl_p = (float*)alloc((size_t)8 * n * 4);
    float*  rowm   = (float*)alloc((size_t)n * 4);
    float*  rowri  = (float*)alloc((size_t)n * 4);
    float*  aggO   = (float*)alloc((size_t)8 * n * MSGC * 4);
    float*  aggM   = (float*)alloc((size_t)8 * n * 4);
    float*  aggL   = (float*)alloc((size_t)8 * n * 4);
    float*  WT     = (float*)alloc((size_t)256 * 96 * 4);
    float*  WaT    = (float*)alloc((size_t)320 * 256 * 4);

    float* hOut = (float*)d_out;
    float* attn = hOut + (size_t)n * H;

    prep_kernel<<<352, 320, 0, stream>>>(Wm, Wk, Wq, Wa, WT, WaT);

    // round 1: fused flash (no stats pass, no attn write)
    proj_kernel<<<n / 8, 128, 0, stream>>>(hs, WT, bm, bk, bq, msgsF, kh, kl, qh, ql, n);
    flash1_kernel<<<dim3(n / 64, 8), 256, 0, stream>>>(qh, ql, kh, kl, msgsF,
                                                       aggO, aggM, aggL, n);
    aggln_kernel<true><<<n / 16, 512, 0, stream>>>(hs, aggO, aggM, aggL,
                                                   WaT, ba, lg, lb, h2, n);
    // round 2: stats (single-pass online) + combine + pass2 (writes normalized attn)
    proj_kernel<<<n / 8, 128, 0, stream>>>(h2, WT, bm, bk, bq, msgsF, kh, kl, qh, ql, n);
    stats_kernel<<<dim3(n / 64, 8), 256, 0, stream>>>(qh, ql, kh, kl, rowm_p, rowl_p, n);
    combine_kernel<<<n / 256, 256, 0, stream>>>(rowm_p, rowl_p, rowm, rowri, n);
    pass2_kernel<<<dim3(n / 64, 8), 256, 0, stream>>>(qh, ql, kh, kl, msgsF,
                                                      rowm, rowri, aggO, attn, n);
    aggln_kernel<false><<<n / 16, 512, 0, stream>>>(h2, aggO, aggM, aggL,
                                                    WaT, ba, lg, lb, hOut, n);
}

// Round 6
// 290.474 us; speedup vs baseline: 2.4427x; 1.0599x over previous
//
#include <hip/hip_runtime.h>

constexpr int H = 256, MSGC = 64;
constexpr float LN_EPS = 1e-5f;
// fold 1/sqrt(16) AND log2(e) into q so softmax exps are single v_exp_f32 (exp2)
constexpr float QSCALE = 0.25f * 1.4426950408889634f;

typedef __attribute__((ext_vector_type(8))) short bf16x8;
typedef __attribute__((ext_vector_type(4))) float f32x4;

__device__ inline ushort f2bf(float x) {
    union { float f; unsigned u; } v; v.f = x;
    unsigned r = v.u + 0x7fffu + ((v.u >> 16) & 1u);
    return (ushort)(r >> 16);
}
__device__ inline float bf2f(ushort h) {
    union { unsigned u; float f; } v; v.u = ((unsigned)h) << 16;
    return v.f;
}
// pack 8 f32 -> bf16x8 via v_cvt_pk_bf16_f32 (RNE), 4 instructions
__device__ inline bf16x8 pack_bf16x8(float4 f0, float4 f1) {
    union { unsigned u[4]; bf16x8 v; } cv;
    asm("v_cvt_pk_bf16_f32 %0, %1, %2" : "=v"(cv.u[0]) : "v"(f0.x), "v"(f0.y));
    asm("v_cvt_pk_bf16_f32 %0, %1, %2" : "=v"(cv.u[1]) : "v"(f0.z), "v"(f0.w));
    asm("v_cvt_pk_bf16_f32 %0, %1, %2" : "=v"(cv.u[2]) : "v"(f1.x), "v"(f1.y));
    asm("v_cvt_pk_bf16_f32 %0, %1, %2" : "=v"(cv.u[3]) : "v"(f1.z), "v"(f1.w));
    return cv.v;
}

// ---------------- prep: WT (proj B, coalesced) + Wa fragment-packed hi/lo ----------------
__global__ __launch_bounds__(256) void prep_kernel(
    const float* __restrict__ Wm, const float* __restrict__ Wk,
    const float* __restrict__ Wq, const float* __restrict__ Wa,
    float* __restrict__ WT, ushort* __restrict__ Wfh, ushort* __restrict__ Wfl)
{
    const int t = threadIdx.x, b = blockIdx.x;
    if (b < 96) {
        const float* src = (b < 64) ? (Wm + (size_t)b * H)
                         : (b < 80) ? (Wk + (size_t)(b - 64) * H)
                                    : (Wq + (size_t)(b - 80) * H);
        WT[(size_t)t * 96 + b] = src[t];
    } else {
        const int unit = b - 96;           // 0..159: ctg = unit/10, kc = unit%10
        const int ctg = unit / 10, kc = unit % 10;
#pragma unroll
        for (int j2 = 0; j2 < 2; ++j2) {
            const int idx = t * 2 + j2;    // 0..511 = lane*8 + e
            const int l = idx >> 3, e = idx & 7;
            const int col = ctg * 16 + (l & 15);
            const int k = kc * 32 + (l >> 4) * 8 + e;
            const float v = Wa[(size_t)col * 320 + k];
            ushort hi = f2bf(v);
            Wfh[(size_t)unit * 512 + idx] = hi;
            Wfl[(size_t)unit * 512 + idx] = f2bf(v - bf2f(hi));
        }
    }
}

// ---------------- proj: 8 rows/block, split-bf16 q/k, fragment-packed msgsF ----------------
__global__ __launch_bounds__(128) void proj_kernel(
    const float* __restrict__ h, const float* __restrict__ WT,
    const float* __restrict__ bm, const float* __restrict__ bk, const float* __restrict__ bq,
    ushort* __restrict__ msgsF, ushort* __restrict__ kh, ushort* __restrict__ kl,
    ushort* __restrict__ qh, ushort* __restrict__ ql, int n)
{
    __shared__ float hl[8 * H];
    const int t = threadIdx.x;
    const int r0 = blockIdx.x * 8;
    const float4* src = (const float4*)(h + (size_t)r0 * H);
    float4* dst = (float4*)hl;
#pragma unroll
    for (int u = 0; u < 4; ++u) dst[t + 128 * u] = src[t + 128 * u];
    __syncthreads();
    if (t < 96) {
        float acc[8];
#pragma unroll
        for (int r = 0; r < 8; ++r) acc[r] = 0.f;
        const float4* h4 = (const float4*)hl;
        for (int k4 = 0; k4 < 64; ++k4) {
            const float* wpt = WT + (size_t)(k4 * 4) * 96 + t;   // coalesced across t
            float w0 = wpt[0], w1 = wpt[96], w2 = wpt[192], w3 = wpt[288];
#pragma unroll
            for (int r = 0; r < 8; ++r) {
                float4 hv = h4[r * 64 + k4];   // uniform address -> LDS broadcast
                acc[r] += hv.x * w0 + hv.y * w1 + hv.z * w2 + hv.w * w3;
            }
        }
        if (t < 64) {
            float bb = bm[t];
#pragma unroll
            for (int r = 0; r < 8; ++r) {
                const int j = r0 + r;
                const size_t idx = ((size_t)(j >> 5) * 4 + (t >> 4)) * 512
                                 + ((j >> 3) & 3) * 128 + (t & 15) * 8 + (j & 7);
                msgsF[idx] = f2bf(acc[r] + bb);
            }
        } else if (t < 80) {
            const int cc = t - 64; float bb = bk[cc];
#pragma unroll
            for (int r = 0; r < 8; ++r) {
                float v = acc[r] + bb;
                ushort hi = f2bf(v);
                kh[(size_t)(r0 + r) * 16 + cc] = hi;
                kl[(size_t)(r0 + r) * 16 + cc] = f2bf(v - bf2f(hi));
            }
        } else {
            const int cc = t - 80; float bb = bq[cc];
#pragma unroll
            for (int r = 0; r < 8; ++r) {
                float v = QSCALE * (acc[r] + bb);
                ushort hi = f2bf(v);
                qh[(size_t)(r0 + r) * 16 + cc] = hi;
                ql[(size_t)(r0 + r) * 16 + cc] = f2bf(v - bf2f(hi));
            }
        }
    }
}

// ---------------- flash1: round-1 attention, no max subtraction, barrier-free ----------------
__global__ __launch_bounds__(256) void flash1_kernel(
    const ushort* __restrict__ qh, const ushort* __restrict__ ql,
    const ushort* __restrict__ kh, const ushort* __restrict__ kl,
    const ushort* __restrict__ msgsF,
    float* __restrict__ aggO, float* __restrict__ aggL, int n)
{
    __shared__ float P[64 * 64];           // 16 KB, XOR-swizzled; waves own disjoint 16-row bands
    const int t = threadIdx.x, lane = t & 63, w = t >> 6;
    const int g = lane >> 4, c = lane & 15;
    const int i0 = blockIdx.x * 64;
    bf16x8 zer = {0,0,0,0,0,0,0,0};
    f32x4 z4 = {0.f, 0.f, 0.f, 0.f};
    const ushort* qsrc = (g < 2) ? qh : ql;
    bf16x8 a1 = *(const bf16x8*)(qsrc + (size_t)(i0 + w * 16 + c) * 16 + 8 * (g & 1));
    bf16x8 a2 = (g < 2) ? a1 : zer;
    float l[4] = {0.f, 0.f, 0.f, 0.f};
    f32x4 accv[4] = {z4, z4, z4, z4};
    const int nj = n / 8, jb = blockIdx.y * nj;
    for (int jt = 0; jt < nj / 64; ++jt) {
        const int j0 = jb + jt * 64;
        bf16x8 b1s[4], b2s[4];
#pragma unroll
        for (int js = 0; js < 4; ++js) {
            const int j = j0 + js * 16 + c;
            b1s[js] = *(const bf16x8*)(kh + (size_t)j * 16 + 8 * (g & 1));
            b2s[js] = (g < 2) ? *(const bf16x8*)(kl + (size_t)j * 16 + 8 * g) : zer;
        }
        f32x4 pd[4];
#pragma unroll
        for (int js = 0; js < 4; ++js) {
            pd[js] = __builtin_amdgcn_mfma_f32_16x16x32_bf16(a1, b1s[js], z4, 0, 0, 0);
            pd[js] = __builtin_amdgcn_mfma_f32_16x16x32_bf16(a2, b2s[js], pd[js], 0, 0, 0);
        }
#pragma unroll
        for (int js = 0; js < 4; ++js) {
#pragma unroll
            for (int r = 0; r < 4; ++r) {
                const int row = w * 16 + g * 4 + r;
                float p = exp2f(pd[js][r]);    // unnormalized; bounded (|s·log2e| << 127)
                l[r] += p;
                const int col = js * 16 + c;
                P[row * 64 + (col ^ ((row & 7) << 2))] = p;
            }
        }
        // PV: own-band only, no barriers
#pragma unroll
        for (int ks = 0; ks < 2; ++ks) {
            const int arow = w * 16 + c;
            const int sw = (arow & 7) << 2;
            const int colb = ks * 32 + 8 * g;
            float4 f0 = *(const float4*)&P[arow * 64 + ((colb) ^ sw)];
            float4 f1 = *(const float4*)&P[arow * 64 + ((colb + 4) ^ sw)];
            bf16x8 af = pack_bf16x8(f0, f1);
            const size_t mbase = ((size_t)(j0 >> 5) + ks) * 4;
#pragma unroll
            for (int mt = 0; mt < 4; ++mt) {
                bf16x8 bfr = *((const bf16x8*)(msgsF + (mbase + mt) * 512) + lane);
                accv[mt] = __builtin_amdgcn_mfma_f32_16x16x32_bf16(af, bfr, accv[mt], 0, 0, 0);
            }
        }
    }
#pragma unroll
    for (int r = 0; r < 4; ++r)
#pragma unroll
        for (int d2 = 1; d2 < 16; d2 <<= 1) l[r] += __shfl_xor(l[r], d2, 64);
#pragma unroll
    for (int mt = 0; mt < 4; ++mt)
#pragma unroll
        for (int r = 0; r < 4; ++r)
            aggO[((size_t)blockIdx.y * n + i0 + w * 16 + g * 4 + r) * MSGC + mt * 16 + c] = accv[mt][r];
    if (c == 0) {
#pragma unroll
        for (int r = 0; r < 4; ++r)
            aggL[(size_t)blockIdx.y * n + i0 + w * 16 + g * 4 + r] = l[r];
    }
}

// ---------------- stats (round 2): row sums of exp2(s), single pass ----------------
__global__ __launch_bounds__(256) void stats_kernel(
    const ushort* __restrict__ qh, const ushort* __restrict__ ql,
    const ushort* __restrict__ kh, const ushort* __restrict__ kl,
    float* __restrict__ rowl_p, int n)
{
    const int t = threadIdx.x, lane = t & 63, w = t >> 6;
    const int g = lane >> 4, c = lane & 15;
    const int iq = blockIdx.x * 64 + w * 16 + c;
    bf16x8 zer = {0,0,0,0,0,0,0,0};
    f32x4 z4 = {0.f, 0.f, 0.f, 0.f};
    const ushort* qsrc = (g < 2) ? qh : ql;
    bf16x8 a1 = *(const bf16x8*)(qsrc + (size_t)iq * 16 + 8 * (g & 1));
    bf16x8 a2 = (g < 2) ? a1 : zer;
    const int nj = n / 8, jb = blockIdx.y * nj;
    float l[4] = {0.f, 0.f, 0.f, 0.f};
    for (int jt = 0; jt < nj / 64; ++jt) {
        const int j0 = jb + jt * 64;
        bf16x8 b1s[4], b2s[4];
#pragma unroll
        for (int js = 0; js < 4; ++js) {
            const int j = j0 + js * 16 + c;
            b1s[js] = *(const bf16x8*)(kh + (size_t)j * 16 + 8 * (g & 1));
            b2s[js] = (g < 2) ? *(const bf16x8*)(kl + (size_t)j * 16 + 8 * g) : zer;
        }
        f32x4 pd[4];
#pragma unroll
        for (int js = 0; js < 4; ++js) {
            pd[js] = __builtin_amdgcn_mfma_f32_16x16x32_bf16(a1, b1s[js], z4, 0, 0, 0);
            pd[js] = __builtin_amdgcn_mfma_f32_16x16x32_bf16(a2, b2s[js], pd[js], 0, 0, 0);
        }
#pragma unroll
        for (int js = 0; js < 4; ++js)
#pragma unroll
            for (int r = 0; r < 4; ++r) l[r] += exp2f(pd[js][r]);
    }
#pragma unroll
    for (int r = 0; r < 4; ++r)
#pragma unroll
        for (int d2 = 1; d2 < 16; d2 <<= 1) l[r] += __shfl_xor(l[r], d2, 64);
    if (c == 0) {
        const int q0 = blockIdx.x * 64 + w * 16 + g * 4;
#pragma unroll
        for (int r = 0; r < 4; ++r)
            rowl_p[(size_t)blockIdx.y * n + q0 + r] = l[r];
    }
}

// ---------------- pass2 (round 2): normalized P -> own-band attn write + PV ----------------
__global__ __launch_bounds__(256) void pass2_kernel(
    const ushort* __restrict__ qh, const ushort* __restrict__ ql,
    const ushort* __restrict__ kh, const ushort* __restrict__ kl,
    const ushort* __restrict__ msgsF, const float* __restrict__ rowl_p,
    float* __restrict__ aggO, float* __restrict__ attn, int n)
{
    __shared__ float P[64 * 64];           // 16 KB; waves own disjoint 16-row bands
    const int t = threadIdx.x, lane = t & 63, w = t >> 6;
    const int g = lane >> 4, c = lane & 15;
    const int i0 = blockIdx.x * 64;
    bf16x8 zer = {0,0,0,0,0,0,0,0};
    f32x4 z4 = {0.f, 0.f, 0.f, 0.f};
    const ushort* qsrc = (g < 2) ? qh : ql;
    bf16x8 a1 = *(const bf16x8*)(qsrc + (size_t)(i0 + w * 16 + c) * 16 + 8 * (g & 1));
    bf16x8 a2 = (g < 2) ? a1 : zer;
    float rinv_r[4];
#pragma unroll
    for (int r = 0; r < 4; ++r) {
        const int q = i0 + w * 16 + g * 4 + r;
        float L = 0.f;
#pragma unroll
        for (int p = 0; p < 8; ++p) L += rowl_p[(size_t)p * n + q];
        rinv_r[r] = 1.f / L;
    }
    f32x4 accv[4] = {z4, z4, z4, z4};
    const int nj = n / 8, jb = blockIdx.y * nj;
    for (int jt = 0; jt < nj / 64; ++jt) {
        const int j0 = jb + jt * 64;
        bf16x8 b1s[4], b2s[4];
#pragma unroll
        for (int js = 0; js < 4; ++js) {
            const int j = j0 + js * 16 + c;
            b1s[js] = *(const bf16x8*)(kh + (size_t)j * 16 + 8 * (g & 1));
            b2s[js] = (g < 2) ? *(const bf16x8*)(kl + (size_t)j * 16 + 8 * g) : zer;
        }
        f32x4 pd[4];
#pragma unroll
        for (int js = 0; js < 4; ++js) {
            pd[js] = __builtin_amdgcn_mfma_f32_16x16x32_bf16(a1, b1s[js], z4, 0, 0, 0);
            pd[js] = __builtin_amdgcn_mfma_f32_16x16x32_bf16(a2, b2s[js], pd[js], 0, 0, 0);
        }
#pragma unroll
        for (int js = 0; js < 4; ++js) {
#pragma unroll
            for (int r = 0; r < 4; ++r) {
                const int row = w * 16 + g * 4 + r;
                const float p = exp2f(pd[js][r]) * rinv_r[r];
                const int col = js * 16 + c;
                P[row * 64 + (col ^ ((row & 7) << 2))] = p;
            }
        }
        // attn write: own band (rows w*16..w*16+15), coalesced 256B per row
#pragma unroll
        for (int u = 0; u < 16; ++u) {
            const int row = w * 16 + u;
            const int sw = (row & 7) << 2;
            attn[(size_t)(i0 + row) * n + j0 + lane] = P[row * 64 + (lane ^ sw)];
        }
        // PV: own band
#pragma unroll
        for (int ks = 0; ks < 2; ++ks) {
            const int arow = w * 16 + c;
            const int sw = (arow & 7) << 2;
            const int colb = ks * 32 + 8 * g;
            float4 f0 = *(const float4*)&P[arow * 64 + ((colb) ^ sw)];
            float4 f1 = *(const float4*)&P[arow * 64 + ((colb + 4) ^ sw)];
            bf16x8 af = pack_bf16x8(f0, f1);
            const size_t mbase = ((size_t)(j0 >> 5) + ks) * 4;
#pragma unroll
            for (int mt = 0; mt < 4; ++mt) {
                bf16x8 bfr = *((const bf16x8*)(msgsF + (mbase + mt) * 512) + lane);
                accv[mt] = __builtin_amdgcn_mfma_f32_16x16x32_bf16(af, bfr, accv[mt], 0, 0, 0);
            }
        }
    }
#pragma unroll
    for (int mt = 0; mt < 4; ++mt)
#pragma unroll
        for (int r = 0; r < 4; ++r) {
            const int row = w * 16 + g * 4 + r;
            aggO[((size_t)blockIdx.y * n + i0 + row) * MSGC + mt * 16 + c] = accv[mt][r];
        }
}

// ---------------- aggln (MFMA): z = [h, agg] @ Wa^T + ba; LayerNorm; ReLU ----------------
// 16 rows/block, 256 thr = 4 waves, wave w owns cols w*64..w*64+63.
// A = dual-split bf16 in LDS (stride 328 -> 2-way-free conflicts); W = fragment-packed hi/lo.
template <bool FLASH>
__global__ __launch_bounds__(256) void aggln_kernel(
    const float* __restrict__ h, const float* __restrict__ aggO,
    const float* __restrict__ aggL,
    const ushort* __restrict__ Wfh, const ushort* __restrict__ Wfl,
    const float* __restrict__ ba,
    const float* __restrict__ gg, const float* __restrict__ bb,
    float* __restrict__ hout, int n)
{
    constexpr int AST = 328;               // ushort row stride (16B-aligned, breaks bank alias)
    __shared__ ushort Ahi[16 * AST];
    __shared__ ushort Alo[16 * AST];
    __shared__ float Linv[16];
    __shared__ float red1[16][4], red2[16][4];
    const int t = threadIdx.x, lane = t & 63, w = t >> 6;
    const int gq = lane >> 4, c = lane & 15;
    const int r0 = blockIdx.x * 16;
    // phase 1: h -> hi/lo split (cols 0..255); t<16 computes Linv
    const float4* hsrc = (const float4*)(h + (size_t)r0 * H);
#pragma unroll
    for (int u = 0; u < 4; ++u) {
        const int idx = t + 256 * u;       // 1024 float4s: 16 rows x 64
        const int row = idx >> 6, c4 = idx & 63;
        float4 v = hsrc[idx];
        ushort4 hi, lo;
        hi.x = f2bf(v.x); lo.x = f2bf(v.x - bf2f(hi.x));
        hi.y = f2bf(v.y); lo.y = f2bf(v.y - bf2f(hi.y));
        hi.z = f2bf(v.z); lo.z = f2bf(v.z - bf2f(hi.z));
        hi.w = f2bf(v.w); lo.w = f2bf(v.w - bf2f(hi.w));
        *(ushort4*)&Ahi[row * AST + c4 * 4] = hi;
        *(ushort4*)&Alo[row * AST + c4 * 4] = lo;
    }
    if (FLASH && t < 16) {
        float L = 0.f;
#pragma unroll
        for (int p = 0; p < 8; ++p) L += aggL[(size_t)p * n + r0 + t];
        Linv[t] = 1.f / L;
    }
    __syncthreads();
    // phase 2: agg sums (cols 256..319)
    {
        const int row = t >> 4, c4 = t & 15;   // 256 float4s
        float4 s = {0.f, 0.f, 0.f, 0.f};
#pragma unroll
        for (int p = 0; p < 8; ++p) {
            const float4 v = *(const float4*)(aggO + (size_t)p * n * MSGC
                               + (size_t)(r0 + row) * MSGC + c4 * 4);
            s.x += v.x; s.y += v.y; s.z += v.z; s.w += v.w;
        }
        if (FLASH) { const float li = Linv[row]; s.x *= li; s.y *= li; s.z *= li; s.w *= li; }
        ushort4 hi, lo;
        hi.x = f2bf(s.x); lo.x = f2bf(s.x - bf2f(hi.x));
        hi.y = f2bf(s.y); lo.y = f2bf(s.y - bf2f(hi.y));
        hi.z = f2bf(s.z); lo.z = f2bf(s.z - bf2f(hi.z));
        hi.w = f2bf(s.w); lo.w = f2bf(s.w - bf2f(hi.w));
        *(ushort4*)&Ahi[row * AST + 256 + c4 * 4] = hi;
        *(ushort4*)&Alo[row * AST + 256 + c4 * 4] = lo;
    }
    __syncthreads();
    // phase 3: MFMA over K=320 (10 chunks), 4 col-tiles per wave, dual-split (3 products)
    f32x4 acc[4] = {{0,0,0,0},{0,0,0,0},{0,0,0,0},{0,0,0,0}};
    for (int kc = 0; kc < 10; ++kc) {
        const bf16x8 afh = *(const bf16x8*)&Ahi[c * AST + kc * 32 + gq * 8];
        const bf16x8 afl = *(const bf16x8*)&Alo[c * AST + kc * 32 + gq * 8];
#pragma unroll
        for (int ct = 0; ct < 4; ++ct) {
            const int ctg = w * 4 + ct;
            const bf16x8 whi = *(const bf16x8*)(Wfh + ((size_t)(ctg * 10 + kc)) * 512 + lane * 8);
            const bf16x8 wlo = *(const bf16x8*)(Wfl + ((size_t)(ctg * 10 + kc)) * 512 + lane * 8);
            acc[ct] = __builtin_amdgcn_mfma_f32_16x16x32_bf16(afh, whi, acc[ct], 0, 0, 0);
            acc[ct] = __builtin_amdgcn_mfma_f32_16x16x32_bf16(afh, wlo, acc[ct], 0, 0, 0);
            acc[ct] = __builtin_amdgcn_mfma_f32_16x16x32_bf16(afl, whi, acc[ct], 0, 0, 0);
        }
    }
    // epilogue: bias -> LN stats (shfl over c-lanes, LDS across waves) -> scale/shift/relu -> store
    float bav[4], gv[4], bv[4];
#pragma unroll
    for (int ct = 0; ct < 4; ++ct) {
        const int col = w * 64 + ct * 16 + c;
        bav[ct] = ba[col]; gv[ct] = gg[col]; bv[ct] = bb[col];
    }
#pragma unroll
    for (int ct = 0; ct < 4; ++ct) {
        acc[ct][0] += bav[ct]; acc[ct][1] += bav[ct];
        acc[ct][2] += bav[ct]; acc[ct][3] += bav[ct];
    }
#pragma unroll
    for (int r = 0; r < 4; ++r) {
        float s1 = 0.f, s2 = 0.f;
#pragma unroll
        for (int ct = 0; ct < 4; ++ct) { const float v = acc[ct][r]; s1 += v; s2 += v * v; }
#pragma unroll
        for (int d = 1; d < 16; d <<= 1) { s1 += __shfl_xor(s1, d, 64); s2 += __shfl_xor(s2, d, 64); }
        if (c == 0) { red1[gq * 4 + r][w] = s1; red2[gq * 4 + r][w] = s2; }
    }
    __syncthreads();
#pragma unroll
    for (int r = 0; r < 4; ++r) {
        const int row = gq * 4 + r;
        const float s1 = red1[row][0] + red1[row][1] + red1[row][2] + red1[row][3];
        const float s2 = red2[row][0] + red2[row][1] + red2[row][2] + red2[row][3];
        const float mu = s1 * (1.f / 256.f);
        const float var = s2 * (1.f / 256.f) - mu * mu;
        const float rs = rsqrtf(var + LN_EPS);
#pragma unroll
        for (int ct = 0; ct < 4; ++ct) {
            float o = (acc[ct][r] - mu) * rs * gv[ct] + bv[ct];
            hout[(size_t)(r0 + row) * H + w * 64 + ct * 16 + c] = fmaxf(o, 0.f);
        }
    }
}

extern "C" void kernel_launch(void* const* d_in, const int* in_sizes, int n_in,
                              void* d_out, int out_size, void* d_ws, size_t ws_size,
                              hipStream_t stream)
{
    const float* hs = (const float*)d_in[0];
    const float* Wm = (const float*)d_in[1];
    const float* bm = (const float*)d_in[2];
    const float* Wk = (const float*)d_in[3];
    const float* bk = (const float*)d_in[4];
    const float* Wq = (const float*)d_in[5];
    const float* bq = (const float*)d_in[6];
    const float* Wa = (const float*)d_in[7];
    const float* ba = (const float*)d_in[8];
    const float* lg = (const float*)d_in[9];
    const float* lb = (const float*)d_in[10];
    const int n = in_sizes[0] / H;         // 8192

    char* wp = (char*)d_ws;
    auto alloc = [&](size_t bytes) { void* p = (void*)wp; wp += (bytes + 255) & ~(size_t)255; return p; };
    float*  h2     = (float*)alloc((size_t)n * H * 4);
    ushort* qh     = (ushort*)alloc((size_t)n * 16 * 2);
    ushort* ql     = (ushort*)alloc((size_t)n * 16 * 2);
    ushort* kh     = (ushort*)alloc((size_t)n * 16 * 2);
    ushort* kl     = (ushort*)alloc((size_t)n * 16 * 2);
    ushort* msgsF  = (ushort*)alloc((size_t)MSGC * n * 2);
    float*  rowl_p = (float*)alloc((size_t)8 * n * 4);
    float*  aggO   = (float*)alloc((size_t)8 * n * MSGC * 4);
    float*  aggL   = (float*)alloc((size_t)8 * n * 4);
    float*  WT     = (float*)alloc((size_t)256 * 96 * 4);
    ushort* Wfh    = (ushort*)alloc((size_t)160 * 512 * 2);
    ushort* Wfl    = (ushort*)alloc((size_t)160 * 512 * 2);

    float* hOut = (float*)d_out;
    float* attn = hOut + (size_t)n * H;

    prep_kernel<<<256, 256, 0, stream>>>(Wm, Wk, Wq, Wa, WT, Wfh, Wfl);

    // round 1: proj -> flash (no max, unnormalized O + L) -> aggln (normalizes)
    proj_kernel<<<n / 8, 128, 0, stream>>>(hs, WT, bm, bk, bq, msgsF, kh, kl, qh, ql, n);
    flash1_kernel<<<dim3(n / 64, 8), 256, 0, stream>>>(qh, ql, kh, kl, msgsF,
                                                       aggO, aggL, n);
    aggln_kernel<true><<<n / 16, 256, 0, stream>>>(hs, aggO, aggL, Wfh, Wfl,
                                                   ba, lg, lb, h2, n);
    // round 2: proj -> stats (row sums) -> pass2 (normalized attn + PV) -> aggln
    proj_kernel<<<n / 8, 128, 0, stream>>>(h2, WT, bm, bk, bq, msgsF, kh, kl, qh, ql, n);
    stats_kernel<<<dim3(n / 64, 8), 256, 0, stream>>>(qh, ql, kh, kl, rowl_p, n);
    pass2_kernel<<<dim3(n / 64, 8), 256, 0, stream>>>(qh, ql, kh, kl, msgsF,
                                                      rowl_p, aggO, attn, n);
    aggln_kernel<false><<<n / 16, 256, 0, stream>>>(h2, aggO, aggL, Wfh, Wfl,
                                                    ba, lg, lb, hOut, n);
}

// Round 7
// 271.933 us; speedup vs baseline: 2.6093x; 1.0682x over previous
//
#include <hip/hip_runtime.h>

constexpr int H = 256, MSGC = 64;
constexpr float LN_EPS = 1e-5f;
// fold 1/sqrt(16) AND log2(e) into q so softmax exps are single v_exp_f32 (exp2)
constexpr float QSCALE = 0.25f * 1.4426950408889634f;

typedef __attribute__((ext_vector_type(8))) short bf16x8;
typedef __attribute__((ext_vector_type(4))) float f32x4;

__device__ inline ushort f2bf(float x) {
    union { float f; unsigned u; } v; v.f = x;
    unsigned r = v.u + 0x7fffu + ((v.u >> 16) & 1u);
    return (ushort)(r >> 16);
}
__device__ inline float bf2f(ushort h) {
    union { unsigned u; float f; } v; v.u = ((unsigned)h) << 16;
    return v.f;
}
// pack 8 f32 -> bf16x8 via v_cvt_pk_bf16_f32 (RNE), 4 instructions
__device__ inline bf16x8 pack_bf16x8(float4 f0, float4 f1) {
    union { unsigned u[4]; bf16x8 v; } cv;
    asm("v_cvt_pk_bf16_f32 %0, %1, %2" : "=v"(cv.u[0]) : "v"(f0.x), "v"(f0.y));
    asm("v_cvt_pk_bf16_f32 %0, %1, %2" : "=v"(cv.u[1]) : "v"(f0.z), "v"(f0.w));
    asm("v_cvt_pk_bf16_f32 %0, %1, %2" : "=v"(cv.u[2]) : "v"(f1.x), "v"(f1.y));
    asm("v_cvt_pk_bf16_f32 %0, %1, %2" : "=v"(cv.u[3]) : "v"(f1.z), "v"(f1.w));
    return cv.v;
}

// ---------------- prep: fragment-pack ALL weights (proj: 48 units; aggln: 160 units) ----------------
// proj unit u = tile*8+kc (tile 0..5: cols {0-63 msg, 64-79 key, 80-95 qry}, kc over K=256)
// frag elem: lane l, e: col = tile*16+(l&15), k = kc*32+(l>>4)*8+e. Wq pre-scaled by QSCALE.
__global__ __launch_bounds__(256) void prep_kernel(
    const float* __restrict__ Wm, const float* __restrict__ Wk,
    const float* __restrict__ Wq, const float* __restrict__ Wa,
    ushort* __restrict__ Wph, ushort* __restrict__ Wpl,
    ushort* __restrict__ Wfh, ushort* __restrict__ Wfl)
{
    const int t = threadIdx.x, b = blockIdx.x;
    if (b < 48) {
        const int tile = b >> 3, kc = b & 7;
#pragma unroll
        for (int j2 = 0; j2 < 2; ++j2) {
            const int idx = t * 2 + j2;
            const int l = idx >> 3, e = idx & 7;
            const int col = tile * 16 + (l & 15);
            const int k = kc * 32 + (l >> 4) * 8 + e;
            float v;
            if (col < 64)      v = Wm[(size_t)col * H + k];
            else if (col < 80) v = Wk[(size_t)(col - 64) * H + k];
            else               v = QSCALE * Wq[(size_t)(col - 80) * H + k];
            ushort hi = f2bf(v);
            Wph[(size_t)b * 512 + idx] = hi;
            Wpl[(size_t)b * 512 + idx] = f2bf(v - bf2f(hi));
        }
    } else {
        const int unit = b - 48;           // 0..159: ctg = unit/10, kc = unit%10
        const int ctg = unit / 10, kc = unit % 10;
#pragma unroll
        for (int j2 = 0; j2 < 2; ++j2) {
            const int idx = t * 2 + j2;
            const int l = idx >> 3, e = idx & 7;
            const int col = ctg * 16 + (l & 15);
            const int k = kc * 32 + (l >> 4) * 8 + e;
            const float v = Wa[(size_t)col * 320 + k];
            ushort hi = f2bf(v);
            Wfh[(size_t)unit * 512 + idx] = hi;
            Wfl[(size_t)unit * 512 + idx] = f2bf(v - bf2f(hi));
        }
    }
}

// ---------------- proj (MFMA): 16 rows/block, 2 waves, dual-split bf16, K=256 ----------------
__global__ __launch_bounds__(128) void proj_kernel(
    const float* __restrict__ h,
    const ushort* __restrict__ Wph, const ushort* __restrict__ Wpl,
    const float* __restrict__ bm, const float* __restrict__ bk, const float* __restrict__ bq,
    ushort* __restrict__ msgsF, ushort* __restrict__ kh, ushort* __restrict__ kl,
    ushort* __restrict__ qh, ushort* __restrict__ ql, int n)
{
    constexpr int AST = 264;               // ushort row stride
    __shared__ ushort Ahi[16 * AST];
    __shared__ ushort Alo[16 * AST];
    const int t = threadIdx.x, lane = t & 63, w = t >> 6;
    const int gq = lane >> 4, c = lane & 15;
    const int r0 = blockIdx.x * 16;
    const float4* hsrc = (const float4*)(h + (size_t)r0 * H);
#pragma unroll
    for (int u = 0; u < 8; ++u) {
        const int idx = t + 128 * u;       // 1024 float4s: 16 rows x 64
        const int row = idx >> 6, c4 = idx & 63;
        float4 v = hsrc[idx];
        ushort4 hi, lo;
        hi.x = f2bf(v.x); lo.x = f2bf(v.x - bf2f(hi.x));
        hi.y = f2bf(v.y); lo.y = f2bf(v.y - bf2f(hi.y));
        hi.z = f2bf(v.z); lo.z = f2bf(v.z - bf2f(hi.z));
        hi.w = f2bf(v.w); lo.w = f2bf(v.w - bf2f(hi.w));
        *(ushort4*)&Ahi[row * AST + c4 * 4] = hi;
        *(ushort4*)&Alo[row * AST + c4 * 4] = lo;
    }
    __syncthreads();
    f32x4 acc[3] = {{0,0,0,0},{0,0,0,0},{0,0,0,0}};
    for (int kc = 0; kc < 8; ++kc) {
        const bf16x8 afh = *(const bf16x8*)&Ahi[c * AST + kc * 32 + gq * 8];
        const bf16x8 afl = *(const bf16x8*)&Alo[c * AST + kc * 32 + gq * 8];
#pragma unroll
        for (int ct = 0; ct < 3; ++ct) {
            const int unit = (w * 3 + ct) * 8 + kc;
            const bf16x8 whi = *(const bf16x8*)(Wph + (size_t)unit * 512 + lane * 8);
            const bf16x8 wlo = *(const bf16x8*)(Wpl + (size_t)unit * 512 + lane * 8);
            acc[ct] = __builtin_amdgcn_mfma_f32_16x16x32_bf16(afh, whi, acc[ct], 0, 0, 0);
            acc[ct] = __builtin_amdgcn_mfma_f32_16x16x32_bf16(afh, wlo, acc[ct], 0, 0, 0);
            acc[ct] = __builtin_amdgcn_mfma_f32_16x16x32_bf16(afl, whi, acc[ct], 0, 0, 0);
        }
    }
    // epilogue: D layout col=c, row=gq*4+r
#pragma unroll
    for (int ct = 0; ct < 3; ++ct) {
        const int tile = w * 3 + ct;
        if (tile < 4) {                    // msgs cols tile*16+c
            const float bb = bm[tile * 16 + c];
#pragma unroll
            for (int r = 0; r < 4; ++r) {
                const int j = r0 + gq * 4 + r;
                const size_t idx = ((size_t)(j >> 5) * 4 + tile) * 512
                                 + ((j >> 3) & 3) * 128 + c * 8 + (j & 7);
                msgsF[idx] = f2bf(acc[ct][r] + bb);
            }
        } else if (tile == 4) {            // keys
            const float bb = bk[c];
#pragma unroll
            for (int r = 0; r < 4; ++r) {
                const int j = r0 + gq * 4 + r;
                const float v = acc[ct][r] + bb;
                const ushort hi = f2bf(v);
                kh[(size_t)j * 16 + c] = hi;
                kl[(size_t)j * 16 + c] = f2bf(v - bf2f(hi));
            }
        } else {                           // qrys (W pre-scaled; scale bias here)
            const float bb = QSCALE * bq[c];
#pragma unroll
            for (int r = 0; r < 4; ++r) {
                const int j = r0 + gq * 4 + r;
                const float v = acc[ct][r] + bb;
                const ushort hi = f2bf(v);
                qh[(size_t)j * 16 + c] = hi;
                ql[(size_t)j * 16 + c] = f2bf(v - bf2f(hi));
            }
        }
    }
}

// ---------------- shared helpers for the attention kernels ----------------
__device__ __forceinline__ void loadK(bf16x8* dst, const ushort* __restrict__ kh,
                                      int j0, int g, int c) {
#pragma unroll
    for (int js = 0; js < 4; ++js)
        dst[js] = *(const bf16x8*)(kh + (size_t)(j0 + js * 16 + c) * 16 + 8 * (g & 1));
}

__device__ __forceinline__ void qk_tile(const bf16x8* b1s, const ushort* __restrict__ kl,
                                        int j0, int g, int c, bf16x8 a1, bf16x8 a2,
                                        const bf16x8 zer, f32x4* pd) {
    const f32x4 z4 = {0.f, 0.f, 0.f, 0.f};
    bf16x8 b2s[4];
#pragma unroll
    for (int js = 0; js < 4; ++js)
        b2s[js] = (g < 2) ? *(const bf16x8*)(kl + (size_t)(j0 + js * 16 + c) * 16 + 8 * g) : zer;
#pragma unroll
    for (int js = 0; js < 4; ++js) {
        pd[js] = __builtin_amdgcn_mfma_f32_16x16x32_bf16(a1, b1s[js], z4, 0, 0, 0);
        pd[js] = __builtin_amdgcn_mfma_f32_16x16x32_bf16(a2, b2s[js], pd[js], 0, 0, 0);
    }
}

__device__ __forceinline__ void pv_tile(const float* __restrict__ P,
                                        const ushort* __restrict__ msgsF,
                                        int j0, int g, int c, int w, int lane, f32x4* accv) {
#pragma unroll
    for (int ks = 0; ks < 2; ++ks) {
        const int arow = w * 16 + c;
        const int sw = (arow & 7) << 2;
        const int colb = ks * 32 + 8 * g;
        float4 f0 = *(const float4*)&P[arow * 64 + ((colb) ^ sw)];
        float4 f1 = *(const float4*)&P[arow * 64 + ((colb + 4) ^ sw)];
        bf16x8 af = pack_bf16x8(f0, f1);
        const size_t mbase = ((size_t)(j0 >> 5) + ks) * 4;
#pragma unroll
        for (int mt = 0; mt < 4; ++mt) {
            bf16x8 bfr = *((const bf16x8*)(msgsF + (mbase + mt) * 512) + lane);
            accv[mt] = __builtin_amdgcn_mfma_f32_16x16x32_bf16(af, bfr, accv[mt], 0, 0, 0);
        }
    }
}

// ---------------- flash1: round-1 attention, no max subtraction, barrier-free, prefetched ----------------
__global__ __launch_bounds__(256) void flash1_kernel(
    const ushort* __restrict__ qh, const ushort* __restrict__ ql,
    const ushort* __restrict__ kh, const ushort* __restrict__ kl,
    const ushort* __restrict__ msgsF,
    float* __restrict__ aggO, float* __restrict__ aggL, int n)
{
    __shared__ float P[64 * 64];
    const int t = threadIdx.x, lane = t & 63, w = t >> 6;
    const int g = lane >> 4, c = lane & 15;
    const int i0 = blockIdx.x * 64;
    bf16x8 zer = {0,0,0,0,0,0,0,0};
    f32x4 z4 = {0.f, 0.f, 0.f, 0.f};
    const ushort* qsrc = (g < 2) ? qh : ql;
    bf16x8 a1 = *(const bf16x8*)(qsrc + (size_t)(i0 + w * 16 + c) * 16 + 8 * (g & 1));
    bf16x8 a2 = (g < 2) ? a1 : zer;
    float l[4] = {0.f, 0.f, 0.f, 0.f};
    f32x4 accv[4] = {z4, z4, z4, z4};
    const int nj = n / 8, jb = blockIdx.y * nj;
    bf16x8 bA[4], bB[4];
    loadK(bA, kh, jb, g, c);
    for (int p = 0; p < 8; ++p) {
        const int t0 = jb + p * 128, t1 = t0 + 64;
        const int t2 = (p < 7) ? t0 + 128 : t1;
        loadK(bB, kh, t1, g, c);
        {
            f32x4 pd[4];
            qk_tile(bA, kl, t0, g, c, a1, a2, zer, pd);
#pragma unroll
            for (int js = 0; js < 4; ++js)
#pragma unroll
                for (int r = 0; r < 4; ++r) {
                    const int row = w * 16 + g * 4 + r;
                    float pp = exp2f(pd[js][r]);
                    l[r] += pp;
                    P[row * 64 + ((js * 16 + c) ^ ((row & 7) << 2))] = pp;
                }
            pv_tile(P, msgsF, t0, g, c, w, lane, accv);
        }
        loadK(bA, kh, t2, g, c);
        {
            f32x4 pd[4];
            qk_tile(bB, kl, t1, g, c, a1, a2, zer, pd);
#pragma unroll
            for (int js = 0; js < 4; ++js)
#pragma unroll
                for (int r = 0; r < 4; ++r) {
                    const int row = w * 16 + g * 4 + r;
                    float pp = exp2f(pd[js][r]);
                    l[r] += pp;
                    P[row * 64 + ((js * 16 + c) ^ ((row & 7) << 2))] = pp;
                }
            pv_tile(P, msgsF, t1, g, c, w, lane, accv);
        }
    }
#pragma unroll
    for (int r = 0; r < 4; ++r)
#pragma unroll
        for (int d2 = 1; d2 < 16; d2 <<= 1) l[r] += __shfl_xor(l[r], d2, 64);
#pragma unroll
    for (int mt = 0; mt < 4; ++mt)
#pragma unroll
        for (int r = 0; r < 4; ++r)
            aggO[((size_t)blockIdx.y * n + i0 + w * 16 + g * 4 + r) * MSGC + mt * 16 + c] = accv[mt][r];
    if (c == 0) {
#pragma unroll
        for (int r = 0; r < 4; ++r)
            aggL[(size_t)blockIdx.y * n + i0 + w * 16 + g * 4 + r] = l[r];
    }
}

// ---------------- stats (round 2): row sums of exp2(s), prefetched ----------------
__global__ __launch_bounds__(256) void stats_kernel(
    const ushort* __restrict__ qh, const ushort* __restrict__ ql,
    const ushort* __restrict__ kh, const ushort* __restrict__ kl,
    float* __restrict__ rowl_p, int n)
{
    const int t = threadIdx.x, lane = t & 63, w = t >> 6;
    const int g = lane >> 4, c = lane & 15;
    const int iq = blockIdx.x * 64 + w * 16 + c;
    bf16x8 zer = {0,0,0,0,0,0,0,0};
    const ushort* qsrc = (g < 2) ? qh : ql;
    bf16x8 a1 = *(const bf16x8*)(qsrc + (size_t)iq * 16 + 8 * (g & 1));
    bf16x8 a2 = (g < 2) ? a1 : zer;
    const int nj = n / 8, jb = blockIdx.y * nj;
    float l[4] = {0.f, 0.f, 0.f, 0.f};
    bf16x8 bA[4], bB[4];
    loadK(bA, kh, jb, g, c);
    for (int p = 0; p < 8; ++p) {
        const int t0 = jb + p * 128, t1 = t0 + 64;
        const int t2 = (p < 7) ? t0 + 128 : t1;
        loadK(bB, kh, t1, g, c);
        {
            f32x4 pd[4];
            qk_tile(bA, kl, t0, g, c, a1, a2, zer, pd);
#pragma unroll
            for (int js = 0; js < 4; ++js)
#pragma unroll
                for (int r = 0; r < 4; ++r) l[r] += exp2f(pd[js][r]);
        }
        loadK(bA, kh, t2, g, c);
        {
            f32x4 pd[4];
            qk_tile(bB, kl, t1, g, c, a1, a2, zer, pd);
#pragma unroll
            for (int js = 0; js < 4; ++js)
#pragma unroll
                for (int r = 0; r < 4; ++r) l[r] += exp2f(pd[js][r]);
        }
    }
#pragma unroll
    for (int r = 0; r < 4; ++r)
#pragma unroll
        for (int d2 = 1; d2 < 16; d2 <<= 1) l[r] += __shfl_xor(l[r], d2, 64);
    if (c == 0) {
        const int q0 = blockIdx.x * 64 + w * 16 + g * 4;
#pragma unroll
        for (int r = 0; r < 4; ++r)
            rowl_p[(size_t)blockIdx.y * n + q0 + r] = l[r];
    }
}

// ---------------- pass2 (round 2): normalized P -> own-band attn write + PV, prefetched ----------------
__global__ __launch_bounds__(256) void pass2_kernel(
    const ushort* __restrict__ qh, const ushort* __restrict__ ql,
    const ushort* __restrict__ kh, const ushort* __restrict__ kl,
    const ushort* __restrict__ msgsF, const float* __restrict__ rowl_p,
    float* __restrict__ aggO, float* __restrict__ attn, int n)
{
    __shared__ float P[64 * 64];
    const int t = threadIdx.x, lane = t & 63, w = t >> 6;
    const int g = lane >> 4, c = lane & 15;
    const int i0 = blockIdx.x * 64;
    bf16x8 zer = {0,0,0,0,0,0,0,0};
    f32x4 z4 = {0.f, 0.f, 0.f, 0.f};
    const ushort* qsrc = (g < 2) ? qh : ql;
    bf16x8 a1 = *(const bf16x8*)(qsrc + (size_t)(i0 + w * 16 + c) * 16 + 8 * (g & 1));
    bf16x8 a2 = (g < 2) ? a1 : zer;
    float rinv_r[4];
#pragma unroll
    for (int r = 0; r < 4; ++r) {
        const int q = i0 + w * 16 + g * 4 + r;
        float L = 0.f;
#pragma unroll
        for (int p = 0; p < 8; ++p) L += rowl_p[(size_t)p * n + q];
        rinv_r[r] = 1.f / L;
    }
    f32x4 accv[4] = {z4, z4, z4, z4};
    const int nj = n / 8, jb = blockIdx.y * nj;
    bf16x8 bA[4], bB[4];
    loadK(bA, kh, jb, g, c);
    for (int p = 0; p < 8; ++p) {
        const int t0 = jb + p * 128, t1 = t0 + 64;
        const int t2 = (p < 7) ? t0 + 128 : t1;
        loadK(bB, kh, t1, g, c);
#pragma unroll
        for (int half = 0; half < 2; ++half) {
            const int j0 = half ? t1 : t0;
            f32x4 pd[4];
            qk_tile(half ? bB : bA, kl, j0, g, c, a1, a2, zer, pd);
            if (half == 0) loadK(bA, kh, t2, g, c);   // keep prefetch for next iter
#pragma unroll
            for (int js = 0; js < 4; ++js)
#pragma unroll
                for (int r = 0; r < 4; ++r) {
                    const int row = w * 16 + g * 4 + r;
                    const float pp = exp2f(pd[js][r]) * rinv_r[r];
                    P[row * 64 + ((js * 16 + c) ^ ((row & 7) << 2))] = pp;
                }
            // attn write: own band, coalesced 256B per row
#pragma unroll
            for (int u = 0; u < 16; ++u) {
                const int row = w * 16 + u;
                const int sw = (row & 7) << 2;
                attn[(size_t)(i0 + row) * n + j0 + lane] = P[row * 64 + (lane ^ sw)];
            }
            pv_tile(P, msgsF, j0, g, c, w, lane, accv);
        }
    }
#pragma unroll
    for (int mt = 0; mt < 4; ++mt)
#pragma unroll
        for (int r = 0; r < 4; ++r) {
            const int row = w * 16 + g * 4 + r;
            aggO[((size_t)blockIdx.y * n + i0 + row) * MSGC + mt * 16 + c] = accv[mt][r];
        }
}

// ---------------- aggln (MFMA): z = [h, agg] @ Wa^T + ba; LayerNorm; ReLU ----------------
template <bool FLASH>
__global__ __launch_bounds__(256) void aggln_kernel(
    const float* __restrict__ h, const float* __restrict__ aggO,
    const float* __restrict__ aggL,
    const ushort* __restrict__ Wfh, const ushort* __restrict__ Wfl,
    const float* __restrict__ ba,
    const float* __restrict__ gg, const float* __restrict__ bb,
    float* __restrict__ hout, int n)
{
    constexpr int AST = 328;
    __shared__ ushort Ahi[16 * AST];
    __shared__ ushort Alo[16 * AST];
    __shared__ float Linv[16];
    __shared__ float red1[16][4], red2[16][4];
    const int t = threadIdx.x, lane = t & 63, w = t >> 6;
    const int gq = lane >> 4, c = lane & 15;
    const int r0 = blockIdx.x * 16;
    const float4* hsrc = (const float4*)(h + (size_t)r0 * H);
#pragma unroll
    for (int u = 0; u < 4; ++u) {
        const int idx = t + 256 * u;
        const int row = idx >> 6, c4 = idx & 63;
        float4 v = hsrc[idx];
        ushort4 hi, lo;
        hi.x = f2bf(v.x); lo.x = f2bf(v.x - bf2f(hi.x));
        hi.y = f2bf(v.y); lo.y = f2bf(v.y - bf2f(hi.y));
        hi.z = f2bf(v.z); lo.z = f2bf(v.z - bf2f(hi.z));
        hi.w = f2bf(v.w); lo.w = f2bf(v.w - bf2f(hi.w));
        *(ushort4*)&Ahi[row * AST + c4 * 4] = hi;
        *(ushort4*)&Alo[row * AST + c4 * 4] = lo;
    }
    if (FLASH && t < 16) {
        float L = 0.f;
#pragma unroll
        for (int p = 0; p < 8; ++p) L += aggL[(size_t)p * n + r0 + t];
        Linv[t] = 1.f / L;
    }
    __syncthreads();
    {
        const int row = t >> 4, c4 = t & 15;
        float4 s = {0.f, 0.f, 0.f, 0.f};
#pragma unroll
        for (int p = 0; p < 8; ++p) {
            const float4 v = *(const float4*)(aggO + (size_t)p * n * MSGC
                               + (size_t)(r0 + row) * MSGC + c4 * 4);
            s.x += v.x; s.y += v.y; s.z += v.z; s.w += v.w;
        }
        if (FLASH) { const float li = Linv[row]; s.x *= li; s.y *= li; s.z *= li; s.w *= li; }
        ushort4 hi, lo;
        hi.x = f2bf(s.x); lo.x = f2bf(s.x - bf2f(hi.x));
        hi.y = f2bf(s.y); lo.y = f2bf(s.y - bf2f(hi.y));
        hi.z = f2bf(s.z); lo.z = f2bf(s.z - bf2f(hi.z));
        hi.w = f2bf(s.w); lo.w = f2bf(s.w - bf2f(hi.w));
        *(ushort4*)&Ahi[row * AST + 256 + c4 * 4] = hi;
        *(ushort4*)&Alo[row * AST + 256 + c4 * 4] = lo;
    }
    __syncthreads();
    f32x4 acc[4] = {{0,0,0,0},{0,0,0,0},{0,0,0,0},{0,0,0,0}};
    for (int kc = 0; kc < 10; ++kc) {
        const bf16x8 afh = *(const bf16x8*)&Ahi[c * AST + kc * 32 + gq * 8];
        const bf16x8 afl = *(const bf16x8*)&Alo[c * AST + kc * 32 + gq * 8];
#pragma unroll
        for (int ct = 0; ct < 4; ++ct) {
            const int ctg = w * 4 + ct;
            const bf16x8 whi = *(const bf16x8*)(Wfh + ((size_t)(ctg * 10 + kc)) * 512 + lane * 8);
            const bf16x8 wlo = *(const bf16x8*)(Wfl + ((size_t)(ctg * 10 + kc)) * 512 + lane * 8);
            acc[ct] = __builtin_amdgcn_mfma_f32_16x16x32_bf16(afh, whi, acc[ct], 0, 0, 0);
            acc[ct] = __builtin_amdgcn_mfma_f32_16x16x32_bf16(afh, wlo, acc[ct], 0, 0, 0);
            acc[ct] = __builtin_amdgcn_mfma_f32_16x16x32_bf16(afl, whi, acc[ct], 0, 0, 0);
        }
    }
    float bav[4], gv[4], bv[4];
#pragma unroll
    for (int ct = 0; ct < 4; ++ct) {
        const int col = w * 64 + ct * 16 + c;
        bav[ct] = ba[col]; gv[ct] = gg[col]; bv[ct] = bb[col];
    }
#pragma unroll
    for (int ct = 0; ct < 4; ++ct) {
        acc[ct][0] += bav[ct]; acc[ct][1] += bav[ct];
        acc[ct][2] += bav[ct]; acc[ct][3] += bav[ct];
    }
#pragma unroll
    for (int r = 0; r < 4; ++r) {
        float s1 = 0.f, s2 = 0.f;
#pragma unroll
        for (int ct = 0; ct < 4; ++ct) { const float v = acc[ct][r]; s1 += v; s2 += v * v; }
#pragma unroll
        for (int d = 1; d < 16; d <<= 1) { s1 += __shfl_xor(s1, d, 64); s2 += __shfl_xor(s2, d, 64); }
        if (c == 0) { red1[gq * 4 + r][w] = s1; red2[gq * 4 + r][w] = s2; }
    }
    __syncthreads();
#pragma unroll
    for (int r = 0; r < 4; ++r) {
        const int row = gq * 4 + r;
        const float s1 = red1[row][0] + red1[row][1] + red1[row][2] + red1[row][3];
        const float s2 = red2[row][0] + red2[row][1] + red2[row][2] + red2[row][3];
        const float mu = s1 * (1.f / 256.f);
        const float var = s2 * (1.f / 256.f) - mu * mu;
        const float rs = rsqrtf(var + LN_EPS);
#pragma unroll
        for (int ct = 0; ct < 4; ++ct) {
            float o = (acc[ct][r] - mu) * rs * gv[ct] + bv[ct];
            hout[(size_t)(r0 + row) * H + w * 64 + ct * 16 + c] = fmaxf(o, 0.f);
        }
    }
}

extern "C" void kernel_launch(void* const* d_in, const int* in_sizes, int n_in,
                              void* d_out, int out_size, void* d_ws, size_t ws_size,
                              hipStream_t stream)
{
    const float* hs = (const float*)d_in[0];
    const float* Wm = (const float*)d_in[1];
    const float* bm = (const float*)d_in[2];
    const float* Wk = (const float*)d_in[3];
    const float* bk = (const float*)d_in[4];
    const float* Wq = (const float*)d_in[5];
    const float* bq = (const float*)d_in[6];
    const float* Wa = (const float*)d_in[7];
    const float* ba = (const float*)d_in[8];
    const float* lg = (const float*)d_in[9];
    const float* lb = (const float*)d_in[10];
    const int n = in_sizes[0] / H;         // 8192

    char* wp = (char*)d_ws;
    auto alloc = [&](size_t bytes) { void* p = (void*)wp; wp += (bytes + 255) & ~(size_t)255; return p; };
    float*  h2     = (float*)alloc((size_t)n * H * 4);
    ushort* qh     = (ushort*)alloc((size_t)n * 16 * 2);
    ushort* ql     = (ushort*)alloc((size_t)n * 16 * 2);
    ushort* kh     = (ushort*)alloc((size_t)n * 16 * 2);
    ushort* kl     = (ushort*)alloc((size_t)n * 16 * 2);
    ushort* msgsF  = (ushort*)alloc((size_t)MSGC * n * 2);
    float*  rowl_p = (float*)alloc((size_t)8 * n * 4);
    float*  aggO   = (float*)alloc((size_t)8 * n * MSGC * 4);
    float*  aggL   = (float*)alloc((size_t)8 * n * 4);
    ushort* Wph    = (ushort*)alloc((size_t)48 * 512 * 2);
    ushort* Wpl    = (ushort*)alloc((size_t)48 * 512 * 2);
    ushort* Wfh    = (ushort*)alloc((size_t)160 * 512 * 2);
    ushort* Wfl    = (ushort*)alloc((size_t)160 * 512 * 2);

    float* hOut = (float*)d_out;
    float* attn = hOut + (size_t)n * H;

    prep_kernel<<<208, 256, 0, stream>>>(Wm, Wk, Wq, Wa, Wph, Wpl, Wfh, Wfl);

    // round 1: proj (MFMA) -> flash (unnormalized O + L) -> aggln (normalizes)
    proj_kernel<<<n / 16, 128, 0, stream>>>(hs, Wph, Wpl, bm, bk, bq, msgsF, kh, kl, qh, ql, n);
    flash1_kernel<<<dim3(n / 64, 8), 256, 0, stream>>>(qh, ql, kh, kl, msgsF,
                                                       aggO, aggL, n);
    aggln_kernel<true><<<n / 16, 256, 0, stream>>>(hs, aggO, aggL, Wfh, Wfl,
                                                   ba, lg, lb, h2, n);
    // round 2: proj -> stats (row sums) -> pass2 (normalized attn + PV) -> aggln
    proj_kernel<<<n / 16, 128, 0, stream>>>(h2, Wph, Wpl, bm, bk, bq, msgsF, kh, kl, qh, ql, n);
    stats_kernel<<<dim3(n / 64, 8), 256, 0, stream>>>(qh, ql, kh, kl, rowl_p, n);
    pass2_kernel<<<dim3(n / 64, 8), 256, 0, stream>>>(qh, ql, kh, kl, msgsF,
                                                      rowl_p, aggO, attn, n);
    aggln_kernel<false><<<n / 16, 256, 0, stream>>>(h2, aggO, aggL, Wfh, Wfl,
                                                    ba, lg, lb, hOut, n);
}

// Round 8
// 244.479 us; speedup vs baseline: 2.9023x; 1.1123x over previous
//
#include <hip/hip_runtime.h>

constexpr int H = 256, MSGC = 64;
constexpr float LN_EPS = 1e-5f;
// fold 1/sqrt(16) AND log2(e) into q so softmax exps are single v_exp_f32 (exp2)
constexpr float QSCALE = 0.25f * 1.4426950408889634f;

typedef __attribute__((ext_vector_type(8))) short bf16x8;
typedef __attribute__((ext_vector_type(4))) float f32x4;

__device__ inline ushort f2bf(float x) {
    union { float f; unsigned u; } v; v.f = x;
    unsigned r = v.u + 0x7fffu + ((v.u >> 16) & 1u);
    return (ushort)(r >> 16);
}
__device__ inline float bf2f(ushort h) {
    union { unsigned u; float f; } v; v.u = ((unsigned)h) << 16;
    return v.f;
}
// pack 8 f32 -> bf16x8 via v_cvt_pk_bf16_f32 (RNE), 4 instructions
__device__ inline bf16x8 pack_bf16x8(float4 f0, float4 f1) {
    union { unsigned u[4]; bf16x8 v; } cv;
    asm("v_cvt_pk_bf16_f32 %0, %1, %2" : "=v"(cv.u[0]) : "v"(f0.x), "v"(f0.y));
    asm("v_cvt_pk_bf16_f32 %0, %1, %2" : "=v"(cv.u[1]) : "v"(f0.z), "v"(f0.w));
    asm("v_cvt_pk_bf16_f32 %0, %1, %2" : "=v"(cv.u[2]) : "v"(f1.x), "v"(f1.y));
    asm("v_cvt_pk_bf16_f32 %0, %1, %2" : "=v"(cv.u[3]) : "v"(f1.z), "v"(f1.w));
    return cv.v;
}

// ---------------- prep: fragment-pack ALL weights (proj: 48 units; aggln: 160 units) ----------------
__global__ __launch_bounds__(256) void prep_kernel(
    const float* __restrict__ Wm, const float* __restrict__ Wk,
    const float* __restrict__ Wq, const float* __restrict__ Wa,
    ushort* __restrict__ Wph, ushort* __restrict__ Wpl,
    ushort* __restrict__ Wfh, ushort* __restrict__ Wfl)
{
    const int t = threadIdx.x, b = blockIdx.x;
    if (b < 48) {
        const int tile = b >> 3, kc = b & 7;
#pragma unroll
        for (int j2 = 0; j2 < 2; ++j2) {
            const int idx = t * 2 + j2;
            const int l = idx >> 3, e = idx & 7;
            const int col = tile * 16 + (l & 15);
            const int k = kc * 32 + (l >> 4) * 8 + e;
            float v;
            if (col < 64)      v = Wm[(size_t)col * H + k];
            else if (col < 80) v = Wk[(size_t)(col - 64) * H + k];
            else               v = QSCALE * Wq[(size_t)(col - 80) * H + k];
            ushort hi = f2bf(v);
            Wph[(size_t)b * 512 + idx] = hi;
            Wpl[(size_t)b * 512 + idx] = f2bf(v - bf2f(hi));
        }
    } else {
        const int unit = b - 48;           // 0..159: ctg = unit/10, kc = unit%10
        const int ctg = unit / 10, kc = unit % 10;
#pragma unroll
        for (int j2 = 0; j2 < 2; ++j2) {
            const int idx = t * 2 + j2;
            const int l = idx >> 3, e = idx & 7;
            const int col = ctg * 16 + (l & 15);
            const int k = kc * 32 + (l >> 4) * 8 + e;
            const float v = Wa[(size_t)col * 320 + k];
            ushort hi = f2bf(v);
            Wfh[(size_t)unit * 512 + idx] = hi;
            Wfl[(size_t)unit * 512 + idx] = f2bf(v - bf2f(hi));
        }
    }
}

// ---------------- proj (MFMA): 16 rows/block, 2 waves, dual-split bf16, K=256 ----------------
__global__ __launch_bounds__(128) void proj_kernel(
    const float* __restrict__ h,
    const ushort* __restrict__ Wph, const ushort* __restrict__ Wpl,
    const float* __restrict__ bm, const float* __restrict__ bk, const float* __restrict__ bq,
    ushort* __restrict__ msgsF, ushort* __restrict__ kh, ushort* __restrict__ kl,
    ushort* __restrict__ qh, ushort* __restrict__ ql, int n)
{
    constexpr int AST = 264;
    __shared__ ushort Ahi[16 * AST];
    __shared__ ushort Alo[16 * AST];
    const int t = threadIdx.x, lane = t & 63, w = t >> 6;
    const int gq = lane >> 4, c = lane & 15;
    const int r0 = blockIdx.x * 16;
    const float4* hsrc = (const float4*)(h + (size_t)r0 * H);
#pragma unroll
    for (int u = 0; u < 8; ++u) {
        const int idx = t + 128 * u;
        const int row = idx >> 6, c4 = idx & 63;
        float4 v = hsrc[idx];
        ushort4 hi, lo;
        hi.x = f2bf(v.x); lo.x = f2bf(v.x - bf2f(hi.x));
        hi.y = f2bf(v.y); lo.y = f2bf(v.y - bf2f(hi.y));
        hi.z = f2bf(v.z); lo.z = f2bf(v.z - bf2f(hi.z));
        hi.w = f2bf(v.w); lo.w = f2bf(v.w - bf2f(hi.w));
        *(ushort4*)&Ahi[row * AST + c4 * 4] = hi;
        *(ushort4*)&Alo[row * AST + c4 * 4] = lo;
    }
    __syncthreads();
    f32x4 acc[3] = {{0,0,0,0},{0,0,0,0},{0,0,0,0}};
    for (int kc = 0; kc < 8; ++kc) {
        const bf16x8 afh = *(const bf16x8*)&Ahi[c * AST + kc * 32 + gq * 8];
        const bf16x8 afl = *(const bf16x8*)&Alo[c * AST + kc * 32 + gq * 8];
#pragma unroll
        for (int ct = 0; ct < 3; ++ct) {
            const int unit = (w * 3 + ct) * 8 + kc;
            const bf16x8 whi = *(const bf16x8*)(Wph + (size_t)unit * 512 + lane * 8);
            const bf16x8 wlo = *(const bf16x8*)(Wpl + (size_t)unit * 512 + lane * 8);
            acc[ct] = __builtin_amdgcn_mfma_f32_16x16x32_bf16(afh, whi, acc[ct], 0, 0, 0);
            acc[ct] = __builtin_amdgcn_mfma_f32_16x16x32_bf16(afh, wlo, acc[ct], 0, 0, 0);
            acc[ct] = __builtin_amdgcn_mfma_f32_16x16x32_bf16(afl, whi, acc[ct], 0, 0, 0);
        }
    }
#pragma unroll
    for (int ct = 0; ct < 3; ++ct) {
        const int tile = w * 3 + ct;
        if (tile < 4) {
            const float bb = bm[tile * 16 + c];
#pragma unroll
            for (int r = 0; r < 4; ++r) {
                const int j = r0 + gq * 4 + r;
                const size_t idx = ((size_t)(j >> 5) * 4 + tile) * 512
                                 + ((j >> 3) & 3) * 128 + c * 8 + (j & 7);
                msgsF[idx] = f2bf(acc[ct][r] + bb);
            }
        } else if (tile == 4) {
            const float bb = bk[c];
#pragma unroll
            for (int r = 0; r < 4; ++r) {
                const int j = r0 + gq * 4 + r;
                const float v = acc[ct][r] + bb;
                const ushort hi = f2bf(v);
                kh[(size_t)j * 16 + c] = hi;
                kl[(size_t)j * 16 + c] = f2bf(v - bf2f(hi));
            }
        } else {
            const float bb = QSCALE * bq[c];
#pragma unroll
            for (int r = 0; r < 4; ++r) {
                const int j = r0 + gq * 4 + r;
                const float v = acc[ct][r] + bb;
                const ushort hi = f2bf(v);
                qh[(size_t)j * 16 + c] = hi;
                ql[(size_t)j * 16 + c] = f2bf(v - bf2f(hi));
            }
        }
    }
}

// ---------------- shared helpers for the attention kernels ----------------
__device__ __forceinline__ void loadK(bf16x8* dst, const ushort* __restrict__ kh,
                                      int j0, int g, int c) {
#pragma unroll
    for (int js = 0; js < 4; ++js)
        dst[js] = *(const bf16x8*)(kh + (size_t)(j0 + js * 16 + c) * 16 + 8 * (g & 1));
}

__device__ __forceinline__ void qk_tile(const bf16x8* b1s, const ushort* __restrict__ kl,
                                        int j0, int g, int c, bf16x8 a1, bf16x8 a2,
                                        const bf16x8 zer, f32x4* pd) {
    const f32x4 z4 = {0.f, 0.f, 0.f, 0.f};
    bf16x8 b2s[4];
#pragma unroll
    for (int js = 0; js < 4; ++js)
        b2s[js] = (g < 2) ? *(const bf16x8*)(kl + (size_t)(j0 + js * 16 + c) * 16 + 8 * g) : zer;
#pragma unroll
    for (int js = 0; js < 4; ++js) {
        pd[js] = __builtin_amdgcn_mfma_f32_16x16x32_bf16(a1, b1s[js], z4, 0, 0, 0);
        pd[js] = __builtin_amdgcn_mfma_f32_16x16x32_bf16(a2, b2s[js], pd[js], 0, 0, 0);
    }
}

__device__ __forceinline__ void pv_tile(const float* __restrict__ P,
                                        const ushort* __restrict__ msgsF,
                                        int j0, int g, int c, int w, int lane, f32x4* accv) {
#pragma unroll
    for (int ks = 0; ks < 2; ++ks) {
        const int arow = w * 16 + c;
        const int sw = (arow & 7) << 2;
        const int colb = ks * 32 + 8 * g;
        float4 f0 = *(const float4*)&P[arow * 64 + ((colb) ^ sw)];
        float4 f1 = *(const float4*)&P[arow * 64 + ((colb + 4) ^ sw)];
        bf16x8 af = pack_bf16x8(f0, f1);
        const size_t mbase = ((size_t)(j0 >> 5) + ks) * 4;
#pragma unroll
        for (int mt = 0; mt < 4; ++mt) {
            bf16x8 bfr = *((const bf16x8*)(msgsF + (mbase + mt) * 512) + lane);
            accv[mt] = __builtin_amdgcn_mfma_f32_16x16x32_bf16(af, bfr, accv[mt], 0, 0, 0);
        }
    }
}

// exp2 + LDS store (unnormalized), accumulating row sums
__device__ __forceinline__ void expstore(const f32x4* pd, float* Pbuf, float* l,
                                         int w, int g, int c) {
#pragma unroll
    for (int js = 0; js < 4; ++js)
#pragma unroll
        for (int r = 0; r < 4; ++r) {
            const int row = w * 16 + g * 4 + r;
            const float pp = exp2f(pd[js][r]);
            l[r] += pp;
            Pbuf[row * 64 + ((js * 16 + c) ^ ((row & 7) << 2))] = pp;
        }
}

// exp2 * rinv + LDS store (normalized)
__device__ __forceinline__ void expstore_n(const f32x4* pd, float* Pbuf, const float* rinv,
                                           int w, int g, int c) {
#pragma unroll
    for (int js = 0; js < 4; ++js)
#pragma unroll
        for (int r = 0; r < 4; ++r) {
            const int row = w * 16 + g * 4 + r;
            const float pp = exp2f(pd[js][r]) * rinv[r];
            Pbuf[row * 64 + ((js * 16 + c) ^ ((row & 7) << 2))] = pp;
        }
}

// own-band attn write: float4 per lane, 4 wave-stores (1KB each)
__device__ __forceinline__ void attn_write(const float* __restrict__ Pbuf,
                                           float* __restrict__ attn,
                                           int i0, int j0, int n, int lane, int w) {
    const int c4 = lane & 15;
#pragma unroll
    for (int u = 0; u < 4; ++u) {
        const int row = w * 16 + u * 4 + (lane >> 4);
        const int sw = (row & 7) << 2;
        float4 v = *(const float4*)&Pbuf[row * 64 + ((c4 * 4) ^ sw)];
        *(float4*)(attn + (size_t)(i0 + row) * n + j0 + c4 * 4) = v;
    }
}

// ---------------- flash1: round-1 attention; P double-buffered, PV lagged one tile ----------------
__global__ __launch_bounds__(256, 4) void flash1_kernel(
    const ushort* __restrict__ qh, const ushort* __restrict__ ql,
    const ushort* __restrict__ kh, const ushort* __restrict__ kl,
    const ushort* __restrict__ msgsF,
    float* __restrict__ aggO, float* __restrict__ aggL, int n)
{
    __shared__ float P0[64 * 64];
    __shared__ float P1[64 * 64];
    const int t = threadIdx.x, lane = t & 63, w = t >> 6;
    const int g = lane >> 4, c = lane & 15;
    const int i0 = blockIdx.x * 64;
    bf16x8 zer = {0,0,0,0,0,0,0,0};
    f32x4 z4 = {0.f, 0.f, 0.f, 0.f};
    const ushort* qsrc = (g < 2) ? qh : ql;
    bf16x8 a1 = *(const bf16x8*)(qsrc + (size_t)(i0 + w * 16 + c) * 16 + 8 * (g & 1));
    bf16x8 a2 = (g < 2) ? a1 : zer;
    float l[4] = {0.f, 0.f, 0.f, 0.f};
    f32x4 accv[4] = {z4, z4, z4, z4};
    const int nj = n / 8, jb = blockIdx.y * nj;   // 16 tiles of 64
    bf16x8 bA[4], bB[4];
    // prologue: tiles 0,1
    loadK(bA, kh, jb, g, c);
    loadK(bB, kh, jb + 64, g, c);
    {
        f32x4 pd[4];
        qk_tile(bA, kl, jb, g, c, a1, a2, zer, pd);
        expstore(pd, P0, l, w, g, c);
    }
    loadK(bA, kh, jb + 128, g, c);
    {
        f32x4 pd[4];
        qk_tile(bB, kl, jb + 64, g, c, a1, a2, zer, pd);
        pv_tile(P0, msgsF, jb, g, c, w, lane, accv);
        expstore(pd, P1, l, w, g, c);
    }
    for (int p = 1; p < 8; ++p) {
        const int tA = jb + p * 128, tB = tA + 64;
        loadK(bB, kh, tB, g, c);
        {
            f32x4 pd[4];
            qk_tile(bA, kl, tA, g, c, a1, a2, zer, pd);
            pv_tile(P1, msgsF, tA - 64, g, c, w, lane, accv);
            expstore(pd, P0, l, w, g, c);
        }
        loadK(bA, kh, (p < 7) ? tA + 128 : tB, g, c);
        {
            f32x4 pd[4];
            qk_tile(bB, kl, tB, g, c, a1, a2, zer, pd);
            pv_tile(P0, msgsF, tA, g, c, w, lane, accv);
            expstore(pd, P1, l, w, g, c);
        }
    }
    pv_tile(P1, msgsF, jb + nj - 64, g, c, w, lane, accv);
#pragma unroll
    for (int r = 0; r < 4; ++r)
#pragma unroll
        for (int d2 = 1; d2 < 16; d2 <<= 1) l[r] += __shfl_xor(l[r], d2, 64);
#pragma unroll
    for (int mt = 0; mt < 4; ++mt)
#pragma unroll
        for (int r = 0; r < 4; ++r)
            aggO[((size_t)blockIdx.y * n + i0 + w * 16 + g * 4 + r) * MSGC + mt * 16 + c] = accv[mt][r];
    if (c == 0) {
#pragma unroll
        for (int r = 0; r < 4; ++r)
            aggL[(size_t)blockIdx.y * n + i0 + w * 16 + g * 4 + r] = l[r];
    }
}

// ---------------- stats (round 2): row sums of exp2(s), prefetched ----------------
__global__ __launch_bounds__(256, 4) void stats_kernel(
    const ushort* __restrict__ qh, const ushort* __restrict__ ql,
    const ushort* __restrict__ kh, const ushort* __restrict__ kl,
    float* __restrict__ rowl_p, int n)
{
    const int t = threadIdx.x, lane = t & 63, w = t >> 6;
    const int g = lane >> 4, c = lane & 15;
    const int iq = blockIdx.x * 64 + w * 16 + c;
    bf16x8 zer = {0,0,0,0,0,0,0,0};
    const ushort* qsrc = (g < 2) ? qh : ql;
    bf16x8 a1 = *(const bf16x8*)(qsrc + (size_t)iq * 16 + 8 * (g & 1));
    bf16x8 a2 = (g < 2) ? a1 : zer;
    const int nj = n / 8, jb = blockIdx.y * nj;
    float l[4] = {0.f, 0.f, 0.f, 0.f};
    bf16x8 bA[4], bB[4];
    loadK(bA, kh, jb, g, c);
    for (int p = 0; p < 8; ++p) {
        const int t0 = jb + p * 128, t1 = t0 + 64;
        const int t2 = (p < 7) ? t0 + 128 : t1;
        loadK(bB, kh, t1, g, c);
        {
            f32x4 pd[4];
            qk_tile(bA, kl, t0, g, c, a1, a2, zer, pd);
#pragma unroll
            for (int js = 0; js < 4; ++js)
#pragma unroll
                for (int r = 0; r < 4; ++r) l[r] += exp2f(pd[js][r]);
        }
        loadK(bA, kh, t2, g, c);
        {
            f32x4 pd[4];
            qk_tile(bB, kl, t1, g, c, a1, a2, zer, pd);
#pragma unroll
            for (int js = 0; js < 4; ++js)
#pragma unroll
                for (int r = 0; r < 4; ++r) l[r] += exp2f(pd[js][r]);
        }
    }
#pragma unroll
    for (int r = 0; r < 4; ++r)
#pragma unroll
        for (int d2 = 1; d2 < 16; d2 <<= 1) l[r] += __shfl_xor(l[r], d2, 64);
    if (c == 0) {
        const int q0 = blockIdx.x * 64 + w * 16 + g * 4;
#pragma unroll
        for (int r = 0; r < 4; ++r)
            rowl_p[(size_t)blockIdx.y * n + q0 + r] = l[r];
    }
}

// ---------------- pass2 (round 2): P double-buffered; attn write + PV lagged one tile ----------------
__global__ __launch_bounds__(256, 4) void pass2_kernel(
    const ushort* __restrict__ qh, const ushort* __restrict__ ql,
    const ushort* __restrict__ kh, const ushort* __restrict__ kl,
    const ushort* __restrict__ msgsF, const float* __restrict__ rowl_p,
    float* __restrict__ aggO, float* __restrict__ attn, int n)
{
    __shared__ float P0[64 * 64];
    __shared__ float P1[64 * 64];
    const int t = threadIdx.x, lane = t & 63, w = t >> 6;
    const int g = lane >> 4, c = lane & 15;
    const int i0 = blockIdx.x * 64;
    bf16x8 zer = {0,0,0,0,0,0,0,0};
    f32x4 z4 = {0.f, 0.f, 0.f, 0.f};
    const ushort* qsrc = (g < 2) ? qh : ql;
    bf16x8 a1 = *(const bf16x8*)(qsrc + (size_t)(i0 + w * 16 + c) * 16 + 8 * (g & 1));
    bf16x8 a2 = (g < 2) ? a1 : zer;
    float rinv[4];
#pragma unroll
    for (int r = 0; r < 4; ++r) {
        const int q = i0 + w * 16 + g * 4 + r;
        float L = 0.f;
#pragma unroll
        for (int p = 0; p < 8; ++p) L += rowl_p[(size_t)p * n + q];
        rinv[r] = 1.f / L;
    }
    f32x4 accv[4] = {z4, z4, z4, z4};
    const int nj = n / 8, jb = blockIdx.y * nj;
    bf16x8 bA[4], bB[4];
    loadK(bA, kh, jb, g, c);
    loadK(bB, kh, jb + 64, g, c);
    {
        f32x4 pd[4];
        qk_tile(bA, kl, jb, g, c, a1, a2, zer, pd);
        expstore_n(pd, P0, rinv, w, g, c);
    }
    loadK(bA, kh, jb + 128, g, c);
    {
        f32x4 pd[4];
        qk_tile(bB, kl, jb + 64, g, c, a1, a2, zer, pd);
        attn_write(P0, attn, i0, jb, n, lane, w);
        pv_tile(P0, msgsF, jb, g, c, w, lane, accv);
        expstore_n(pd, P1, rinv, w, g, c);
    }
    for (int p = 1; p < 8; ++p) {
        const int tA = jb + p * 128, tB = tA + 64;
        loadK(bB, kh, tB, g, c);
        {
            f32x4 pd[4];
            qk_tile(bA, kl, tA, g, c, a1, a2, zer, pd);
            attn_write(P1, attn, i0, tA - 64, n, lane, w);
            pv_tile(P1, msgsF, tA - 64, g, c, w, lane, accv);
            expstore_n(pd, P0, rinv, w, g, c);
        }
        loadK(bA, kh, (p < 7) ? tA + 128 : tB, g, c);
        {
            f32x4 pd[4];
            qk_tile(bB, kl, tB, g, c, a1, a2, zer, pd);
            attn_write(P0, attn, i0, tA, n, lane, w);
            pv_tile(P0, msgsF, tA, g, c, w, lane, accv);
            expstore_n(pd, P1, rinv, w, g, c);
        }
    }
    attn_write(P1, attn, i0, jb + nj - 64, n, lane, w);
    pv_tile(P1, msgsF, jb + nj - 64, g, c, w, lane, accv);
#pragma unroll
    for (int mt = 0; mt < 4; ++mt)
#pragma unroll
        for (int r = 0; r < 4; ++r) {
            const int row = w * 16 + g * 4 + r;
            aggO[((size_t)blockIdx.y * n + i0 + row) * MSGC + mt * 16 + c] = accv[mt][r];
        }
}

// ---------------- aggln (MFMA): z = [h, agg] @ Wa^T + ba; LayerNorm; ReLU ----------------
template <bool FLASH>
__global__ __launch_bounds__(256) void aggln_kernel(
    const float* __restrict__ h, const float* __restrict__ aggO,
    const float* __restrict__ aggL,
    const ushort* __restrict__ Wfh, const ushort* __restrict__ Wfl,
    const float* __restrict__ ba,
    const float* __restrict__ gg, const float* __restrict__ bb,
    float* __restrict__ hout, int n)
{
    constexpr int AST = 328;
    __shared__ ushort Ahi[16 * AST];
    __shared__ ushort Alo[16 * AST];
    __shared__ float Linv[16];
    __shared__ float red1[16][4], red2[16][4];
    const int t = threadIdx.x, lane = t & 63, w = t >> 6;
    const int gq = lane >> 4, c = lane & 15;
    const int r0 = blockIdx.x * 16;
    const float4* hsrc = (const float4*)(h + (size_t)r0 * H);
#pragma unroll
    for (int u = 0; u < 4; ++u) {
        const int idx = t + 256 * u;
        const int row = idx >> 6, c4 = idx & 63;
        float4 v = hsrc[idx];
        ushort4 hi, lo;
        hi.x = f2bf(v.x); lo.x = f2bf(v.x - bf2f(hi.x));
        hi.y = f2bf(v.y); lo.y = f2bf(v.y - bf2f(hi.y));
        hi.z = f2bf(v.z); lo.z = f2bf(v.z - bf2f(hi.z));
        hi.w = f2bf(v.w); lo.w = f2bf(v.w - bf2f(hi.w));
        *(ushort4*)&Ahi[row * AST + c4 * 4] = hi;
        *(ushort4*)&Alo[row * AST + c4 * 4] = lo;
    }
    if (FLASH && t < 16) {
        float L = 0.f;
#pragma unroll
        for (int p = 0; p < 8; ++p) L += aggL[(size_t)p * n + r0 + t];
        Linv[t] = 1.f / L;
    }
    __syncthreads();
    {
        const int row = t >> 4, c4 = t & 15;
        float4 s = {0.f, 0.f, 0.f, 0.f};
#pragma unroll
        for (int p = 0; p < 8; ++p) {
            const float4 v = *(const float4*)(aggO + (size_t)p * n * MSGC
                               + (size_t)(r0 + row) * MSGC + c4 * 4);
            s.x += v.x; s.y += v.y; s.z += v.z; s.w += v.w;
        }
        if (FLASH) { const float li = Linv[row]; s.x *= li; s.y *= li; s.z *= li; s.w *= li; }
        ushort4 hi, lo;
        hi.x = f2bf(s.x); lo.x = f2bf(s.x - bf2f(hi.x));
        hi.y = f2bf(s.y); lo.y = f2bf(s.y - bf2f(hi.y));
        hi.z = f2bf(s.z); lo.z = f2bf(s.z - bf2f(hi.z));
        hi.w = f2bf(s.w); lo.w = f2bf(s.w - bf2f(hi.w));
        *(ushort4*)&Ahi[row * AST + 256 + c4 * 4] = hi;
        *(ushort4*)&Alo[row * AST + 256 + c4 * 4] = lo;
    }
    __syncthreads();
    f32x4 acc[4] = {{0,0,0,0},{0,0,0,0},{0,0,0,0},{0,0,0,0}};
    for (int kc = 0; kc < 10; ++kc) {
        const bf16x8 afh = *(const bf16x8*)&Ahi[c * AST + kc * 32 + gq * 8];
        const bf16x8 afl = *(const bf16x8*)&Alo[c * AST + kc * 32 + gq * 8];
#pragma unroll
        for (int ct = 0; ct < 4; ++ct) {
            const int ctg = w * 4 + ct;
            const bf16x8 whi = *(const bf16x8*)(Wfh + ((size_t)(ctg * 10 + kc)) * 512 + lane * 8);
            const bf16x8 wlo = *(const bf16x8*)(Wfl + ((size_t)(ctg * 10 + kc)) * 512 + lane * 8);
            acc[ct] = __builtin_amdgcn_mfma_f32_16x16x32_bf16(afh, whi, acc[ct], 0, 0, 0);
            acc[ct] = __builtin_amdgcn_mfma_f32_16x16x32_bf16(afh, wlo, acc[ct], 0, 0, 0);
            acc[ct] = __builtin_amdgcn_mfma_f32_16x16x32_bf16(afl, whi, acc[ct], 0, 0, 0);
        }
    }
    float bav[4], gv[4], bv[4];
#pragma unroll
    for (int ct = 0; ct < 4; ++ct) {
        const int col = w * 64 + ct * 16 + c;
        bav[ct] = ba[col]; gv[ct] = gg[col]; bv[ct] = bb[col];
    }
#pragma unroll
    for (int ct = 0; ct < 4; ++ct) {
        acc[ct][0] += bav[ct]; acc[ct][1] += bav[ct];
        acc[ct][2] += bav[ct]; acc[ct][3] += bav[ct];
    }
#pragma unroll
    for (int r = 0; r < 4; ++r) {
        float s1 = 0.f, s2 = 0.f;
#pragma unroll
        for (int ct = 0; ct < 4; ++ct) { const float v = acc[ct][r]; s1 += v; s2 += v * v; }
#pragma unroll
        for (int d = 1; d < 16; d <<= 1) { s1 += __shfl_xor(s1, d, 64); s2 += __shfl_xor(s2, d, 64); }
        if (c == 0) { red1[gq * 4 + r][w] = s1; red2[gq * 4 + r][w] = s2; }
    }
    __syncthreads();
#pragma unroll
    for (int r = 0; r < 4; ++r) {
        const int row = gq * 4 + r;
        const float s1 = red1[row][0] + red1[row][1] + red1[row][2] + red1[row][3];
        const float s2 = red2[row][0] + red2[row][1] + red2[row][2] + red2[row][3];
        const float mu = s1 * (1.f / 256.f);
        const float var = s2 * (1.f / 256.f) - mu * mu;
        const float rs = rsqrtf(var + LN_EPS);
#pragma unroll
        for (int ct = 0; ct < 4; ++ct) {
            float o = (acc[ct][r] - mu) * rs * gv[ct] + bv[ct];
            hout[(size_t)(r0 + row) * H + w * 64 + ct * 16 + c] = fmaxf(o, 0.f);
        }
    }
}

extern "C" void kernel_launch(void* const* d_in, const int* in_sizes, int n_in,
                              void* d_out, int out_size, void* d_ws, size_t ws_size,
                              hipStream_t stream)
{
    const float* hs = (const float*)d_in[0];
    const float* Wm = (const float*)d_in[1];
    const float* bm = (const float*)d_in[2];
    const float* Wk = (const float*)d_in[3];
    const float* bk = (const float*)d_in[4];
    const float* Wq = (const float*)d_in[5];
    const float* bq = (const float*)d_in[6];
    const float* Wa = (const float*)d_in[7];
    const float* ba = (const float*)d_in[8];
    const float* lg = (const float*)d_in[9];
    const float* lb = (const float*)d_in[10];
    const int n = in_sizes[0] / H;         // 8192

    char* wp = (char*)d_ws;
    auto alloc = [&](size_t bytes) { void* p = (void*)wp; wp += (bytes + 255) & ~(size_t)255; return p; };
    float*  h2     = (float*)alloc((size_t)n * H * 4);
    ushort* qh     = (ushort*)alloc((size_t)n * 16 * 2);
    ushort* ql     = (ushort*)alloc((size_t)n * 16 * 2);
    ushort* kh     = (ushort*)alloc((size_t)n * 16 * 2);
    ushort* kl     = (ushort*)alloc((size_t)n * 16 * 2);
    ushort* msgsF  = (ushort*)alloc((size_t)MSGC * n * 2);
    float*  rowl_p = (float*)alloc((size_t)8 * n * 4);
    float*  aggO   = (float*)alloc((size_t)8 * n * MSGC * 4);
    float*  aggL   = (float*)alloc((size_t)8 * n * 4);
    ushort* Wph    = (ushort*)alloc((size_t)48 * 512 * 2);
    ushort* Wpl    = (ushort*)alloc((size_t)48 * 512 * 2);
    ushort* Wfh    = (ushort*)alloc((size_t)160 * 512 * 2);
    ushort* Wfl    = (ushort*)alloc((size_t)160 * 512 * 2);

    float* hOut = (float*)d_out;
    float* attn = hOut + (size_t)n * H;

    prep_kernel<<<208, 256, 0, stream>>>(Wm, Wk, Wq, Wa, Wph, Wpl, Wfh, Wfl);

    // round 1: proj (MFMA) -> flash (unnormalized O + L) -> aggln (normalizes)
    proj_kernel<<<n / 16, 128, 0, stream>>>(hs, Wph, Wpl, bm, bk, bq, msgsF, kh, kl, qh, ql, n);
    flash1_kernel<<<dim3(n / 64, 8), 256, 0, stream>>>(qh, ql, kh, kl, msgsF,
                                                       aggO, aggL, n);
    aggln_kernel<true><<<n / 16, 256, 0, stream>>>(hs, aggO, aggL, Wfh, Wfl,
                                                   ba, lg, lb, h2, n);
    // round 2: proj -> stats (row sums) -> pass2 (normalized attn + PV) -> aggln
    proj_kernel<<<n / 16, 128, 0, stream>>>(h2, Wph, Wpl, bm, bk, bq, msgsF, kh, kl, qh, ql, n);
    stats_kernel<<<dim3(n / 64, 8), 256, 0, stream>>>(qh, ql, kh, kl, rowl_p, n);
    pass2_kernel<<<dim3(n / 64, 8), 256, 0, stream>>>(qh, ql, kh, kl, msgsF,
                                                      rowl_p, aggO, attn, n);
    aggln_kernel<false><<<n / 16, 256, 0, stream>>>(h2, aggO, aggL, Wfh, Wfl,
                                                    ba, lg, lb, hOut, n);
}